// Round 7
// baseline (256.805 us; speedup 1.0000x reference)
//
#include <hip/hip_runtime.h>
#include <cstdint>
#include <cstddef>

// ---------------------------------------------------------------------------
// GCN: out = relu(BN2(A' relu(BN1(A' BN0(X) W1)) W2)) Wf + bf
// A' = D^-1/2 (A+I) D^-1/2 via per-call CSR (sorted by dst).
// Conv biases b1,b2 cancel inside the following BatchNorm and are skipped.
// BN affine (a,b per column) is fused into GEMM X-staging.
// GEMMs 128x128 use bf16 MFMA (16x16x32); hidden H stored bf16 (halves the
// random-gather traffic). AGG kept fp32.
// BN1/BN2 stats FUSED into k_aggregate; aggregate is ONE WAVE PER NODE
// (r6: grid-stride 2048-block form dropped occupancy 65->37% and BW 3.7->2.2
// TB/s from load imbalance — max wave count wins for the latency-bound gather).
// CSR fill uses ranks captured from k_count's atomicAdd return (no 2nd atomic).
// No float atomics / no threadfence anywhere (r3: fence idled the chip).
// ---------------------------------------------------------------------------

#define CS_BLOCKS 512

typedef short s8v __attribute__((ext_vector_type(8)));
typedef float f4v __attribute__((ext_vector_type(4)));

__device__ inline ushort f2bf(float f) {            // RNE float->bf16
    uint u = __float_as_uint(f);
    return (ushort)((u + 0x7fffu + ((u >> 16) & 1u)) >> 16);
}
__device__ inline float2 bf2f2(uint u) {            // packed 2xbf16 -> 2xf32
    float2 r;
    r.x = __uint_as_float(u << 16);
    r.y = __uint_as_float(u & 0xffff0000u);
    return r;
}

// ---- per-block column partials for X0 (sum, sumsq) ------------------------
__global__ __launch_bounds__(256) void k_colstats(const float* __restrict__ X,
                                                  int n,
                                                  float* __restrict__ part) {
    __shared__ float ls[8 * 128];
    __shared__ float lq[8 * 128];
    const int c4    = threadIdx.x & 31;
    const int rslot = threadIdx.x >> 5;
    float4 s4 = make_float4(0.f, 0.f, 0.f, 0.f);
    float4 q4 = make_float4(0.f, 0.f, 0.f, 0.f);
    const float4* X4 = (const float4*)X;
    for (int r = blockIdx.x * 8 + rslot; r < n; r += CS_BLOCKS * 8) {
        float4 v = X4[(size_t)r * 32 + c4];
        s4.x += v.x; s4.y += v.y; s4.z += v.z; s4.w += v.w;
        q4.x = fmaf(v.x, v.x, q4.x); q4.y = fmaf(v.y, v.y, q4.y);
        q4.z = fmaf(v.z, v.z, q4.z); q4.w = fmaf(v.w, v.w, q4.w);
    }
    *(float4*)&ls[rslot * 128 + c4 * 4] = s4;
    *(float4*)&lq[rslot * 128 + c4 * 4] = q4;
    __syncthreads();
    float t = 0.f;
    if (threadIdx.x < 128) {
        int c = threadIdx.x;
        #pragma unroll
        for (int k = 0; k < 8; ++k) t += ls[k * 128 + c];
    } else {
        int c = threadIdx.x - 128;
        #pragma unroll
        for (int k = 0; k < 8; ++k) t += lq[k * 128 + c];
    }
    part[blockIdx.x * 256 + threadIdx.x] = t;
}

// ---- collapse nrows partial rows -> 64 rows (coalesced, bounds-checked) ---
__global__ __launch_bounds__(256) void k_redA(const float* __restrict__ part,
                                              float* __restrict__ part2,
                                              int nrows) {
    const int c = threadIdx.x;
    const int b = blockIdx.x;           // 64 blocks
    const int per = (nrows + 63) >> 6;
    const int r0 = b * per;
    const int r1 = min(r0 + per, nrows);
    float t0 = 0.f, t1 = 0.f;
    int r = r0;
    for (; r + 2 <= r1; r += 2) {
        t0 += part[(size_t)r * 256 + c];
        t1 += part[(size_t)(r + 1) * 256 + c];
    }
    if (r < r1) t0 += part[(size_t)r * 256 + c];
    part2[b * 256 + c] = t0 + t1;
}

// ---- reduce partial rows, emit BN affine (a,b). nrows % 16 == 0 -----------
__global__ __launch_bounds__(1024) void k_bnfinal(const float* __restrict__ part,
                                                  int nrows,
                                                  const float* __restrict__ g,
                                                  const float* __restrict__ be,
                                                  float invn,
                                                  float* __restrict__ a,
                                                  float* __restrict__ b) {
    __shared__ float sh[4][256];
    const int c = threadIdx.x & 255;
    const int q = threadIdx.x >> 8;
    const int per = nrows >> 2;
    float t = 0.f;
    for (int r = q * per; r < q * per + per; r += 4) {
        t += part[(r + 0) * 256 + c] + part[(r + 1) * 256 + c]
           + part[(r + 2) * 256 + c] + part[(r + 3) * 256 + c];
    }
    sh[q][c] = t;
    __syncthreads();
    if (threadIdx.x < 128) {
        int cc = threadIdx.x;
        float su = sh[0][cc] + sh[1][cc] + sh[2][cc] + sh[3][cc];
        float sq = sh[0][cc + 128] + sh[1][cc + 128]
                 + sh[2][cc + 128] + sh[3][cc + 128];
        float mu  = su * invn;
        float var = sq * invn - mu * mu;
        float av  = g[cc] * rsqrtf(var + 1e-5f);
        a[cc] = av;
        b[cc] = be[cc] - mu * av;
    }
}

// ---- CSR build ------------------------------------------------------------
// count also captures each edge's within-node rank (atomicAdd return value),
// so k_fill needs no second atomic pass.
__global__ __launch_bounds__(256) void k_count(const int* __restrict__ dst, int e,
                                               int* __restrict__ cnt,
                                               int* __restrict__ rank) {
    int i = blockIdx.x * 256 + threadIdx.x;
    if (i < e) rank[i] = atomicAdd(&cnt[dst[i]], 1);
}

__global__ __launch_bounds__(1024) void k_scanA(const int* __restrict__ cnt, int n,
                                                int* __restrict__ rs, int* __restrict__ bsum) {
    __shared__ int tmp[1024];
    int t = threadIdx.x;
    int i = blockIdx.x * 1024 + t;
    int v = (i < n) ? cnt[i] : 0;
    tmp[t] = v;
    __syncthreads();
    for (int off = 1; off < 1024; off <<= 1) {
        int x = (t >= off) ? tmp[t - off] : 0;
        __syncthreads();
        tmp[t] += x;
        __syncthreads();
    }
    if (i < n) rs[i] = tmp[t] - v;
    if (t == 1023) bsum[blockIdx.x] = tmp[t];
}

__global__ __launch_bounds__(256) void k_scanC(int* __restrict__ rs,
                                               const int* __restrict__ bsum,
                                               const int* __restrict__ cnt,
                                               float* __restrict__ dinv,
                                               int n, int e) {
    __shared__ int base;
    int chunk = (int)(blockIdx.x >> 2);
    if (threadIdx.x == 0) {
        int s = 0;
        for (int c = 0; c < chunk; ++c) s += bsum[c];
        base = s;
    }
    __syncthreads();
    int i = blockIdx.x * 256 + threadIdx.x;
    if (i < n) {
        rs[i] += base;
        dinv[i] = rsqrtf((float)(cnt[i] + 1));
    }
    if (blockIdx.x == 0 && threadIdx.x == 0) rs[n] = e;
}

__global__ __launch_bounds__(256) void k_fill(const int* __restrict__ src,
                                              const int* __restrict__ dst, int e,
                                              const int* __restrict__ rs,
                                              const int* __restrict__ rank,
                                              const float* __restrict__ dinv,
                                              int2* __restrict__ ep) {
    int i = blockIdx.x * 256 + threadIdx.x;
    if (i < e) {
        int d = dst[i], s = src[i];
        int p = rs[d] + rank[i];
        float nm = dinv[s] * dinv[d];
        ep[p] = make_int2(s, __float_as_int(nm));
    }
}

// ---- W pre-swizzle to MFMA frag order -------------------------------------
__global__ __launch_bounds__(256) void k_prep_w(const float* __restrict__ W,
                                                ushort* __restrict__ Wswz) {
    int t  = blockIdx.x * 256 + threadIdx.x;   // 0..2047
    int l  = t & 63;
    int fi = t >> 6;
    int ks = fi & 3, ct = fi >> 2;
    int c  = ct * 16 + (l & 15);
    int k0 = ks * 32 + ((l >> 4) << 3);
    ushort o[8];
    #pragma unroll
    for (int j = 0; j < 8; ++j)
        o[j] = f2bf(W[(size_t)(k0 + j) * 128 + c]);
    ushort4* dst = (ushort4*)(Wswz + (size_t)t * 8);
    dst[0] = make_ushort4(o[0], o[1], o[2], o[3]);
    dst[1] = make_ushort4(o[4], o[5], o[6], o[7]);
}

// ---- MFMA GEMM: H_bf16[n][128] = bf16( f(X) @ W ) -------------------------
__global__ __launch_bounds__(256) void k_gemm_mfma(const float* __restrict__ X,
                                                   const ushort* __restrict__ Wswz,
                                                   const float* __restrict__ av,
                                                   const float* __restrict__ bv,
                                                   int relu,
                                                   ushort* __restrict__ H, int n) {
    __shared__ ushort xb[64 * 128];   // 16 KB, swizzled: byte ^= (row&7)<<4
    const int tid  = threadIdx.x;
    const int row0 = blockIdx.x * 64;

    for (int i = tid; i < 64 * 32; i += 256) {
        int r = i >> 5, c4 = i & 31;
        int gr = row0 + r;
        float4 v = make_float4(0.f, 0.f, 0.f, 0.f);
        if (gr < n) v = ((const float4*)X)[(size_t)gr * 32 + c4];
        float4 a4 = ((const float4*)av)[c4];
        float4 b4 = ((const float4*)bv)[c4];
        v.x = fmaf(v.x, a4.x, b4.x);
        v.y = fmaf(v.y, a4.y, b4.y);
        v.z = fmaf(v.z, a4.z, b4.z);
        v.w = fmaf(v.w, a4.w, b4.w);
        if (relu) {
            v.x = fmaxf(v.x, 0.f); v.y = fmaxf(v.y, 0.f);
            v.z = fmaxf(v.z, 0.f); v.w = fmaxf(v.w, 0.f);
        }
        ushort4 pk = make_ushort4(f2bf(v.x), f2bf(v.y), f2bf(v.z), f2bf(v.w));
        int off = (r * 256 + c4 * 8) ^ ((r & 7) << 4);
        *(ushort4*)((char*)xb + off) = pk;
    }
    __syncthreads();

    const int wv = tid >> 6;
    const int l  = tid & 63;
    const int arow = wv * 16 + (l & 15);

    s8v afr[4];
    #pragma unroll
    for (int ks = 0; ks < 4; ++ks) {
        int off = (arow * 256 + ks * 64 + ((l >> 4) << 4)) ^ ((arow & 7) << 4);
        afr[ks] = *(const s8v*)((const char*)xb + off);
    }

    const s8v* wf = (const s8v*)Wswz;
    f4v acc[8];
    #pragma unroll
    for (int ct = 0; ct < 8; ++ct) {
        f4v c = {0.f, 0.f, 0.f, 0.f};
        #pragma unroll
        for (int ks = 0; ks < 4; ++ks) {
            s8v bb = wf[(ct * 4 + ks) * 64 + l];
            c = __builtin_amdgcn_mfma_f32_16x16x32_bf16(afr[ks], bb, c, 0, 0, 0);
        }
        acc[ct] = c;
    }

    const int rbase = row0 + wv * 16 + ((l >> 4) << 2);
    const int cidx  = l & 15;
    #pragma unroll
    for (int r = 0; r < 4; ++r) {
        int gr = rbase + r;
        if (gr < n) {
            #pragma unroll
            for (int ct = 0; ct < 8; ++ct)
                H[(size_t)gr * 128 + ct * 16 + cidx] = f2bf(acc[ct][r]);
        }
    }
}

// ---- aggregation + fused BN stats: ONE WAVE PER NODE ----------------------
// Block = 4 waves = 4 nodes; per-lane sum/sumsq of the stored fp32 acc is
// LDS-reduced across the block into part[block][256].
__global__ __launch_bounds__(256) void k_aggregate(const ushort* __restrict__ H,
                                                   const int* __restrict__ rs,
                                                   const int2* __restrict__ ep,
                                                   const float* __restrict__ dinv,
                                                   float* __restrict__ AGG,
                                                   float* __restrict__ part, int n) {
    __shared__ float red[4][128];
    __shared__ float redq[4][128];
    const int wv   = threadIdx.x >> 6;
    const int lane = threadIdx.x & 63;
    const int node = blockIdx.x * 4 + wv;
    float sx = 0.f, sy = 0.f, qx = 0.f, qy = 0.f;

    if (node < n) {
        float sn = dinv[node]; sn *= sn;
        float2 self = bf2f2(((const uint*)(H + (size_t)node * 128))[lane]);
        float2 acc;
        acc.x = self.x * sn; acc.y = self.y * sn;
        int i  = rs[node];
        int i1 = rs[node + 1];
        for (; i + 16 <= i1; i += 16) {
            int2 p[16];
            uint v[16];
            #pragma unroll
            for (int k = 0; k < 16; ++k) p[k] = ep[i + k];
            #pragma unroll
            for (int k = 0; k < 16; ++k)
                v[k] = ((const uint*)(H + (size_t)p[k].x * 128))[lane];
            #pragma unroll
            for (int k = 0; k < 16; ++k) {
                float w = __int_as_float(p[k].y);
                float2 f = bf2f2(v[k]);
                acc.x = fmaf(w, f.x, acc.x);
                acc.y = fmaf(w, f.y, acc.y);
            }
        }
        if (i + 8 <= i1) {
            int2 p[8];
            uint v[8];
            #pragma unroll
            for (int k = 0; k < 8; ++k) p[k] = ep[i + k];
            #pragma unroll
            for (int k = 0; k < 8; ++k)
                v[k] = ((const uint*)(H + (size_t)p[k].x * 128))[lane];
            #pragma unroll
            for (int k = 0; k < 8; ++k) {
                float w = __int_as_float(p[k].y);
                float2 f = bf2f2(v[k]);
                acc.x = fmaf(w, f.x, acc.x);
                acc.y = fmaf(w, f.y, acc.y);
            }
            i += 8;
        }
        if (i + 4 <= i1) {
            int2 p[4];
            uint v[4];
            #pragma unroll
            for (int k = 0; k < 4; ++k) p[k] = ep[i + k];
            #pragma unroll
            for (int k = 0; k < 4; ++k)
                v[k] = ((const uint*)(H + (size_t)p[k].x * 128))[lane];
            #pragma unroll
            for (int k = 0; k < 4; ++k) {
                float w = __int_as_float(p[k].y);
                float2 f = bf2f2(v[k]);
                acc.x = fmaf(w, f.x, acc.x);
                acc.y = fmaf(w, f.y, acc.y);
            }
            i += 4;
        }
        for (; i < i1; ++i) {
            int2 p = ep[i];
            float w = __int_as_float(p.y);
            float2 f = bf2f2(((const uint*)(H + (size_t)p.x * 128))[lane]);
            acc.x = fmaf(w, f.x, acc.x);
            acc.y = fmaf(w, f.y, acc.y);
        }
        ((float2*)(AGG + (size_t)node * 128))[lane] = acc;
        sx = acc.x; sy = acc.y;
        qx = acc.x * acc.x;
        qy = acc.y * acc.y;
    }

    red[wv][2 * lane]      = sx;
    red[wv][2 * lane + 1]  = sy;
    redq[wv][2 * lane]     = qx;
    redq[wv][2 * lane + 1] = qy;
    __syncthreads();
    const int t = threadIdx.x;
    if (t < 128)
        part[(size_t)blockIdx.x * 256 + t] =
            red[0][t] + red[1][t] + red[2][t] + red[3][t];
    else {
        int c = t - 128;
        part[(size_t)blockIdx.x * 256 + t] =
            redq[0][c] + redq[1][c] + redq[2][c] + redq[3][c];
    }
}

// ---- final projection: OUT = relu(a*X+b) @ Wf + bf  (128 -> 40) -----------
__global__ __launch_bounds__(256) void k_gemm_out(const float* __restrict__ X,
                                                  const float* __restrict__ Wf,
                                                  const float* __restrict__ bfv,
                                                  const float* __restrict__ a,
                                                  const float* __restrict__ b,
                                                  float* __restrict__ OUT, int n) {
    __shared__ float xl[32 * 132];
    __shared__ float wt[40 * 132];
    const int tid = threadIdx.x;

    for (int i = tid; i < 128 * 40; i += 256) {
        int c = i / 40;
        int j = i - c * 40;
        wt[j * 132 + c] = Wf[i];
    }
    const int row0 = blockIdx.x * 32;
    for (int i = tid; i < 32 * 32; i += 256) {
        int r = i >> 5, c4 = i & 31;
        int gr = row0 + r;
        float4 v = make_float4(0.f, 0.f, 0.f, 0.f);
        if (gr < n) v = ((const float4*)X)[(size_t)gr * 32 + c4];
        float4 a4 = ((const float4*)a)[c4];
        float4 b4 = ((const float4*)b)[c4];
        v.x = fmaxf(fmaf(v.x, a4.x, b4.x), 0.f);
        v.y = fmaxf(fmaf(v.y, a4.y, b4.y), 0.f);
        v.z = fmaxf(fmaf(v.z, a4.z, b4.z), 0.f);
        v.w = fmaxf(fmaf(v.w, a4.w, b4.w), 0.f);
        *(float4*)&xl[r * 132 + (c4 << 2)] = v;
    }
    __syncthreads();

    const int rg = tid >> 3;
    const int cg = tid & 7;
    const int j0 = cg * 5;
    float acc[5] = {0.f, 0.f, 0.f, 0.f, 0.f};
    for (int c = 0; c < 128; c += 4) {
        float4 xv = *(const float4*)&xl[rg * 132 + c];
        #pragma unroll
        for (int j = 0; j < 5; ++j) {
            float4 wv = *(const float4*)&wt[(j0 + j) * 132 + c];
            acc[j] = fmaf(xv.x, wv.x, acc[j]);
            acc[j] = fmaf(xv.y, wv.y, acc[j]);
            acc[j] = fmaf(xv.z, wv.z, acc[j]);
            acc[j] = fmaf(xv.w, wv.w, acc[j]);
        }
    }
    int gr = row0 + rg;
    if (gr < n) {
        #pragma unroll
        for (int j = 0; j < 5; ++j)
            OUT[(size_t)gr * 40 + j0 + j] = acc[j] + bfv[j0 + j];
    }
}

// ---------------------------------------------------------------------------
extern "C" void kernel_launch(void* const* d_in, const int* in_sizes, int n_in,
                              void* d_out, int out_size, void* d_ws, size_t ws_size,
                              hipStream_t stream) {
    const float* X0      = (const float*)d_in[0];
    const int*   edgesrc = (const int*)d_in[1];
    const int*   edgedst = (const int*)d_in[2];
    const float* bn0g = (const float*)d_in[3];
    const float* bn0b = (const float*)d_in[4];
    const float* W1   = (const float*)d_in[5];
    const float* bn1g = (const float*)d_in[7];
    const float* bn1b = (const float*)d_in[8];
    const float* W2   = (const float*)d_in[9];
    const float* bn2g = (const float*)d_in[11];
    const float* bn2b = (const float*)d_in[12];
    const float* Wf   = (const float*)d_in[13];
    const float* bfv  = (const float*)d_in[14];

    const int n = in_sizes[0] / 128;
    const int e = in_sizes[1];
    float* OUT = (float*)d_out;

    const int aggBlocks = (n + 3) / 4;               // one wave per node

    // workspace layout
    ushort* H    = (ushort*)d_ws;                     // n*128 bf16
    float*  AGG  = (float*)(H + (size_t)n * 128);     // n*128 f32
    float*  dinv = AGG + (size_t)n * 128;             // n
    int2*   ep   = (int2*)(dinv + n);                 // e
    ushort* Wswz = (ushort*)(ep + e);                 // 2 * 16384 bf16
    int*    cnt  = (int*)(Wswz + 2 * 16384);          // n
    int*    rs   = cnt + n;                           // n+1
    int*    rank = rs + n + 1;                        // e
    int*    bsum = rank + e;                          // 64
    float*  part = (float*)(bsum + 64);               // aggBlocks*256 (12.8MB)
    float* part2 = part + (size_t)aggBlocks * 256;    // 64*256
    float* a0 = part2 + 64 * 256;       float* b0 = a0 + 128;
    float* a1 = b0 + 128;               float* b1 = a1 + 128;
    float* a2 = b1 + 128;               float* b2 = a2 + 128;

    hipMemsetAsync(cnt, 0, (size_t)n * sizeof(int), stream);

    const float invn = 1.f / (float)n;
    const int nb = (n + 1023) / 1024;

    k_prep_w<<<8, 256, 0, stream>>>(W1, Wswz);
    k_prep_w<<<8, 256, 0, stream>>>(W2, Wswz + 16384);

    // CSR build
    k_count<<<(e + 255) / 256, 256, 0, stream>>>(edgedst, e, cnt, rank);
    k_scanA<<<nb, 1024, 0, stream>>>(cnt, n, rs, bsum);
    k_scanC<<<(n + 255) / 256, 256, 0, stream>>>(rs, bsum, cnt, dinv, n, e);
    k_fill<<<(e + 255) / 256, 256, 0, stream>>>(edgesrc, edgedst, e, rs, rank,
                                                dinv, ep);

    const int gemmBlocks = (n + 63) / 64;

    // layer 1
    k_colstats<<<CS_BLOCKS, 256, 0, stream>>>(X0, n, part);
    k_bnfinal<<<1, 1024, 0, stream>>>(part, CS_BLOCKS, bn0g, bn0b, invn, a0, b0);
    k_gemm_mfma<<<gemmBlocks, 256, 0, stream>>>(X0, Wswz, a0, b0, 0, H, n);
    k_aggregate<<<aggBlocks, 256, 0, stream>>>(H, rs, ep, dinv, AGG, part, n);

    // layer 2 (stats of AGG came fused from aggregate)
    k_redA<<<64, 256, 0, stream>>>(part, part2, aggBlocks);
    k_bnfinal<<<1, 1024, 0, stream>>>(part2, 64, bn1g, bn1b, invn, a1, b1);
    k_gemm_mfma<<<gemmBlocks, 256, 0, stream>>>(AGG, Wswz + 16384, a1, b1, 1, H, n);
    k_aggregate<<<aggBlocks, 256, 0, stream>>>(H, rs, ep, dinv, AGG, part, n);

    // head
    k_redA<<<64, 256, 0, stream>>>(part, part2, aggBlocks);
    k_bnfinal<<<1, 1024, 0, stream>>>(part2, 64, bn2g, bn2b, invn, a2, b2);
    k_gemm_out<<<(n + 31) / 32, 256, 0, stream>>>(AGG, Wf, bfv, a2, b2, OUT, n);
}

// Round 8
// 251.452 us; speedup vs baseline: 1.0213x; 1.0213x over previous
//
#include <hip/hip_runtime.h>
#include <cstdint>
#include <cstddef>

// ---------------------------------------------------------------------------
// GCN: out = relu(BN2(A' relu(BN1(A' BN0(X) W1)) W2)) Wf + bf
// A' = D^-1/2 (A+I) D^-1/2 via per-call CSR (sorted by dst).
// Conv biases b1,b2 cancel inside the following BatchNorm and are skipped.
// BN affine (a,b per column) is fused into GEMM X-staging.
// GEMMs 128x128 use bf16 MFMA (16x16x32); hidden H stored bf16 (halves the
// random-gather traffic). AGG kept fp32.
// BN1/BN2 stats FUSED into k_aggregate (one wave per node; r6: grid-stride
// dropped occupancy 65->37% from load imbalance).
// NO hipMemsetAsync: the runtime's fillBufferAligned ran at 5 GB/s (41 us for
// 200 KB, measured r7) inside the graph — cnt zeroing is fused into k_init.
// No float atomics / no threadfence anywhere (r3: fence idled the chip).
// ---------------------------------------------------------------------------

#define CS_BLOCKS 512

typedef short s8v __attribute__((ext_vector_type(8)));
typedef float f4v __attribute__((ext_vector_type(4)));

__device__ inline ushort f2bf(float f) {            // RNE float->bf16
    uint u = __float_as_uint(f);
    return (ushort)((u + 0x7fffu + ((u >> 16) & 1u)) >> 16);
}
__device__ inline float2 bf2f2(uint u) {            // packed 2xbf16 -> 2xf32
    float2 r;
    r.x = __uint_as_float(u << 16);
    r.y = __uint_as_float(u & 0xffff0000u);
    return r;
}

// ---- fused init: W1/W2 frag-swizzle + cnt zero ----------------------------
// Frag fi = ct*4+ks: 64 lanes x 8 bf16; lane l holds
// W[k = 32*ks + 8*(l>>4) + j][c = 16*ct + (l&15)], j=0..7.
// blocks 0..7: W1 -> Wswz[0..]; blocks 8..15: W2 -> Wswz[16384..];
// blocks 16..79: zero cnt[n] (int4-vectorized).
__global__ __launch_bounds__(256) void k_init(const float* __restrict__ W1,
                                              const float* __restrict__ W2,
                                              ushort* __restrict__ Wswz,
                                              int* __restrict__ cnt, int n) {
    const int bid = blockIdx.x;
    if (bid < 16) {
        const float* W = (bid < 8) ? W1 : W2;
        ushort* out = Wswz + (bid < 8 ? 0 : 16384);
        int t  = (bid & 7) * 256 + threadIdx.x;   // 0..2047
        int l  = t & 63;
        int fi = t >> 6;
        int ks = fi & 3, ct = fi >> 2;
        int c  = ct * 16 + (l & 15);
        int k0 = ks * 32 + ((l >> 4) << 3);
        ushort o[8];
        #pragma unroll
        for (int j = 0; j < 8; ++j)
            o[j] = f2bf(W[(size_t)(k0 + j) * 128 + c]);
        ushort4* dst = (ushort4*)(out + (size_t)t * 8);
        dst[0] = make_ushort4(o[0], o[1], o[2], o[3]);
        dst[1] = make_ushort4(o[4], o[5], o[6], o[7]);
    } else {
        const int nv = n >> 2;                    // int4 count
        int4* c4 = (int4*)cnt;
        const int4 z = make_int4(0, 0, 0, 0);
        for (int i = (bid - 16) * 256 + threadIdx.x; i < nv; i += 64 * 256)
            c4[i] = z;
        // tail
        int tail0 = nv << 2;
        int i = tail0 + (bid - 16) * 256 + threadIdx.x;
        if (i < n) cnt[i] = 0;
    }
}

// ---- per-block column partials for X0 (sum, sumsq) ------------------------
__global__ __launch_bounds__(256) void k_colstats(const float* __restrict__ X,
                                                  int n,
                                                  float* __restrict__ part) {
    __shared__ float ls[8 * 128];
    __shared__ float lq[8 * 128];
    const int c4    = threadIdx.x & 31;
    const int rslot = threadIdx.x >> 5;
    float4 s4 = make_float4(0.f, 0.f, 0.f, 0.f);
    float4 q4 = make_float4(0.f, 0.f, 0.f, 0.f);
    const float4* X4 = (const float4*)X;
    for (int r = blockIdx.x * 8 + rslot; r < n; r += CS_BLOCKS * 8) {
        float4 v = X4[(size_t)r * 32 + c4];
        s4.x += v.x; s4.y += v.y; s4.z += v.z; s4.w += v.w;
        q4.x = fmaf(v.x, v.x, q4.x); q4.y = fmaf(v.y, v.y, q4.y);
        q4.z = fmaf(v.z, v.z, q4.z); q4.w = fmaf(v.w, v.w, q4.w);
    }
    *(float4*)&ls[rslot * 128 + c4 * 4] = s4;
    *(float4*)&lq[rslot * 128 + c4 * 4] = q4;
    __syncthreads();
    float t = 0.f;
    if (threadIdx.x < 128) {
        int c = threadIdx.x;
        #pragma unroll
        for (int k = 0; k < 8; ++k) t += ls[k * 128 + c];
    } else {
        int c = threadIdx.x - 128;
        #pragma unroll
        for (int k = 0; k < 8; ++k) t += lq[k * 128 + c];
    }
    part[blockIdx.x * 256 + threadIdx.x] = t;
}

// ---- collapse nrows partial rows -> 64 rows (coalesced, bounds-checked) ---
__global__ __launch_bounds__(256) void k_redA(const float* __restrict__ part,
                                              float* __restrict__ part2,
                                              int nrows) {
    const int c = threadIdx.x;
    const int b = blockIdx.x;           // 64 blocks
    const int per = (nrows + 63) >> 6;
    const int r0 = b * per;
    const int r1 = min(r0 + per, nrows);
    float t0 = 0.f, t1 = 0.f;
    int r = r0;
    for (; r + 2 <= r1; r += 2) {
        t0 += part[(size_t)r * 256 + c];
        t1 += part[(size_t)(r + 1) * 256 + c];
    }
    if (r < r1) t0 += part[(size_t)r * 256 + c];
    part2[b * 256 + c] = t0 + t1;
}

// ---- reduce partial rows, emit BN affine (a,b). nrows % 16 == 0 -----------
__global__ __launch_bounds__(1024) void k_bnfinal(const float* __restrict__ part,
                                                  int nrows,
                                                  const float* __restrict__ g,
                                                  const float* __restrict__ be,
                                                  float invn,
                                                  float* __restrict__ a,
                                                  float* __restrict__ b) {
    __shared__ float sh[4][256];
    const int c = threadIdx.x & 255;
    const int q = threadIdx.x >> 8;
    const int per = nrows >> 2;
    float t = 0.f;
    for (int r = q * per; r < q * per + per; r += 4) {
        t += part[(r + 0) * 256 + c] + part[(r + 1) * 256 + c]
           + part[(r + 2) * 256 + c] + part[(r + 3) * 256 + c];
    }
    sh[q][c] = t;
    __syncthreads();
    if (threadIdx.x < 128) {
        int cc = threadIdx.x;
        float su = sh[0][cc] + sh[1][cc] + sh[2][cc] + sh[3][cc];
        float sq = sh[0][cc + 128] + sh[1][cc + 128]
                 + sh[2][cc + 128] + sh[3][cc + 128];
        float mu  = su * invn;
        float var = sq * invn - mu * mu;
        float av  = g[cc] * rsqrtf(var + 1e-5f);
        a[cc] = av;
        b[cc] = be[cc] - mu * av;
    }
}

// ---- CSR build ------------------------------------------------------------
__global__ __launch_bounds__(256) void k_count(const int* __restrict__ dst, int e,
                                               int* __restrict__ cnt,
                                               int* __restrict__ rank) {
    int i = blockIdx.x * 256 + threadIdx.x;
    if (i < e) rank[i] = atomicAdd(&cnt[dst[i]], 1);
}

__global__ __launch_bounds__(1024) void k_scanA(const int* __restrict__ cnt, int n,
                                                int* __restrict__ rs, int* __restrict__ bsum) {
    __shared__ int tmp[1024];
    int t = threadIdx.x;
    int i = blockIdx.x * 1024 + t;
    int v = (i < n) ? cnt[i] : 0;
    tmp[t] = v;
    __syncthreads();
    for (int off = 1; off < 1024; off <<= 1) {
        int x = (t >= off) ? tmp[t - off] : 0;
        __syncthreads();
        tmp[t] += x;
        __syncthreads();
    }
    if (i < n) rs[i] = tmp[t] - v;
    if (t == 1023) bsum[blockIdx.x] = tmp[t];
}

__global__ __launch_bounds__(256) void k_scanC(int* __restrict__ rs,
                                               const int* __restrict__ bsum,
                                               const int* __restrict__ cnt,
                                               float* __restrict__ dinv,
                                               int n, int e) {
    __shared__ int base;
    int chunk = (int)(blockIdx.x >> 2);
    if (threadIdx.x == 0) {
        int s = 0;
        for (int c = 0; c < chunk; ++c) s += bsum[c];
        base = s;
    }
    __syncthreads();
    int i = blockIdx.x * 256 + threadIdx.x;
    if (i < n) {
        rs[i] += base;
        dinv[i] = rsqrtf((float)(cnt[i] + 1));
    }
    if (blockIdx.x == 0 && threadIdx.x == 0) rs[n] = e;
}

__global__ __launch_bounds__(256) void k_fill(const int* __restrict__ src,
                                              const int* __restrict__ dst, int e,
                                              const int* __restrict__ rs,
                                              const int* __restrict__ rank,
                                              const float* __restrict__ dinv,
                                              int2* __restrict__ ep) {
    int i = blockIdx.x * 256 + threadIdx.x;
    if (i < e) {
        int d = dst[i], s = src[i];
        int p = rs[d] + rank[i];
        float nm = dinv[s] * dinv[d];
        ep[p] = make_int2(s, __float_as_int(nm));
    }
}

// ---- MFMA GEMM: H_bf16[n][128] = bf16( f(X) @ W ) -------------------------
__global__ __launch_bounds__(256) void k_gemm_mfma(const float* __restrict__ X,
                                                   const ushort* __restrict__ Wswz,
                                                   const float* __restrict__ av,
                                                   const float* __restrict__ bv,
                                                   int relu,
                                                   ushort* __restrict__ H, int n) {
    __shared__ ushort xb[64 * 128];   // 16 KB, swizzled: byte ^= (row&7)<<4
    const int tid  = threadIdx.x;
    const int row0 = blockIdx.x * 64;

    for (int i = tid; i < 64 * 32; i += 256) {
        int r = i >> 5, c4 = i & 31;
        int gr = row0 + r;
        float4 v = make_float4(0.f, 0.f, 0.f, 0.f);
        if (gr < n) v = ((const float4*)X)[(size_t)gr * 32 + c4];
        float4 a4 = ((const float4*)av)[c4];
        float4 b4 = ((const float4*)bv)[c4];
        v.x = fmaf(v.x, a4.x, b4.x);
        v.y = fmaf(v.y, a4.y, b4.y);
        v.z = fmaf(v.z, a4.z, b4.z);
        v.w = fmaf(v.w, a4.w, b4.w);
        if (relu) {
            v.x = fmaxf(v.x, 0.f); v.y = fmaxf(v.y, 0.f);
            v.z = fmaxf(v.z, 0.f); v.w = fmaxf(v.w, 0.f);
        }
        ushort4 pk = make_ushort4(f2bf(v.x), f2bf(v.y), f2bf(v.z), f2bf(v.w));
        int off = (r * 256 + c4 * 8) ^ ((r & 7) << 4);
        *(ushort4*)((char*)xb + off) = pk;
    }
    __syncthreads();

    const int wv = tid >> 6;
    const int l  = tid & 63;
    const int arow = wv * 16 + (l & 15);

    s8v afr[4];
    #pragma unroll
    for (int ks = 0; ks < 4; ++ks) {
        int off = (arow * 256 + ks * 64 + ((l >> 4) << 4)) ^ ((arow & 7) << 4);
        afr[ks] = *(const s8v*)((const char*)xb + off);
    }

    const s8v* wf = (const s8v*)Wswz;
    f4v acc[8];
    #pragma unroll
    for (int ct = 0; ct < 8; ++ct) {
        f4v c = {0.f, 0.f, 0.f, 0.f};
        #pragma unroll
        for (int ks = 0; ks < 4; ++ks) {
            s8v bb = wf[(ct * 4 + ks) * 64 + l];
            c = __builtin_amdgcn_mfma_f32_16x16x32_bf16(afr[ks], bb, c, 0, 0, 0);
        }
        acc[ct] = c;
    }

    const int rbase = row0 + wv * 16 + ((l >> 4) << 2);
    const int cidx  = l & 15;
    #pragma unroll
    for (int r = 0; r < 4; ++r) {
        int gr = rbase + r;
        if (gr < n) {
            #pragma unroll
            for (int ct = 0; ct < 8; ++ct)
                H[(size_t)gr * 128 + ct * 16 + cidx] = f2bf(acc[ct][r]);
        }
    }
}

// ---- aggregation + fused BN stats: ONE WAVE PER NODE ----------------------
__global__ __launch_bounds__(256) void k_aggregate(const ushort* __restrict__ H,
                                                   const int* __restrict__ rs,
                                                   const int2* __restrict__ ep,
                                                   const float* __restrict__ dinv,
                                                   float* __restrict__ AGG,
                                                   float* __restrict__ part, int n) {
    __shared__ float red[4][128];
    __shared__ float redq[4][128];
    const int wv   = threadIdx.x >> 6;
    const int lane = threadIdx.x & 63;
    const int node = blockIdx.x * 4 + wv;
    float sx = 0.f, sy = 0.f, qx = 0.f, qy = 0.f;

    if (node < n) {
        float sn = dinv[node]; sn *= sn;
        float2 self = bf2f2(((const uint*)(H + (size_t)node * 128))[lane]);
        float2 acc;
        acc.x = self.x * sn; acc.y = self.y * sn;
        int i  = rs[node];
        int i1 = rs[node + 1];
        for (; i + 16 <= i1; i += 16) {
            int2 p[16];
            uint v[16];
            #pragma unroll
            for (int k = 0; k < 16; ++k) p[k] = ep[i + k];
            #pragma unroll
            for (int k = 0; k < 16; ++k)
                v[k] = ((const uint*)(H + (size_t)p[k].x * 128))[lane];
            #pragma unroll
            for (int k = 0; k < 16; ++k) {
                float w = __int_as_float(p[k].y);
                float2 f = bf2f2(v[k]);
                acc.x = fmaf(w, f.x, acc.x);
                acc.y = fmaf(w, f.y, acc.y);
            }
        }
        if (i + 8 <= i1) {
            int2 p[8];
            uint v[8];
            #pragma unroll
            for (int k = 0; k < 8; ++k) p[k] = ep[i + k];
            #pragma unroll
            for (int k = 0; k < 8; ++k)
                v[k] = ((const uint*)(H + (size_t)p[k].x * 128))[lane];
            #pragma unroll
            for (int k = 0; k < 8; ++k) {
                float w = __int_as_float(p[k].y);
                float2 f = bf2f2(v[k]);
                acc.x = fmaf(w, f.x, acc.x);
                acc.y = fmaf(w, f.y, acc.y);
            }
            i += 8;
        }
        if (i + 4 <= i1) {
            int2 p[4];
            uint v[4];
            #pragma unroll
            for (int k = 0; k < 4; ++k) p[k] = ep[i + k];
            #pragma unroll
            for (int k = 0; k < 4; ++k)
                v[k] = ((const uint*)(H + (size_t)p[k].x * 128))[lane];
            #pragma unroll
            for (int k = 0; k < 4; ++k) {
                float w = __int_as_float(p[k].y);
                float2 f = bf2f2(v[k]);
                acc.x = fmaf(w, f.x, acc.x);
                acc.y = fmaf(w, f.y, acc.y);
            }
            i += 4;
        }
        for (; i < i1; ++i) {
            int2 p = ep[i];
            float w = __int_as_float(p.y);
            float2 f = bf2f2(((const uint*)(H + (size_t)p.x * 128))[lane]);
            acc.x = fmaf(w, f.x, acc.x);
            acc.y = fmaf(w, f.y, acc.y);
        }
        ((float2*)(AGG + (size_t)node * 128))[lane] = acc;
        sx = acc.x; sy = acc.y;
        qx = acc.x * acc.x;
        qy = acc.y * acc.y;
    }

    red[wv][2 * lane]      = sx;
    red[wv][2 * lane + 1]  = sy;
    redq[wv][2 * lane]     = qx;
    redq[wv][2 * lane + 1] = qy;
    __syncthreads();
    const int t = threadIdx.x;
    if (t < 128)
        part[(size_t)blockIdx.x * 256 + t] =
            red[0][t] + red[1][t] + red[2][t] + red[3][t];
    else {
        int c = t - 128;
        part[(size_t)blockIdx.x * 256 + t] =
            redq[0][c] + redq[1][c] + redq[2][c] + redq[3][c];
    }
}

// ---- final projection: OUT = relu(a*X+b) @ Wf + bf  (128 -> 40) -----------
__global__ __launch_bounds__(256) void k_gemm_out(const float* __restrict__ X,
                                                  const float* __restrict__ Wf,
                                                  const float* __restrict__ bfv,
                                                  const float* __restrict__ a,
                                                  const float* __restrict__ b,
                                                  float* __restrict__ OUT, int n) {
    __shared__ float xl[32 * 132];
    __shared__ float wt[40 * 132];
    const int tid = threadIdx.x;

    for (int i = tid; i < 128 * 40; i += 256) {
        int c = i / 40;
        int j = i - c * 40;
        wt[j * 132 + c] = Wf[i];
    }
    const int row0 = blockIdx.x * 32;
    for (int i = tid; i < 32 * 32; i += 256) {
        int r = i >> 5, c4 = i & 31;
        int gr = row0 + r;
        float4 v = make_float4(0.f, 0.f, 0.f, 0.f);
        if (gr < n) v = ((const float4*)X)[(size_t)gr * 32 + c4];
        float4 a4 = ((const float4*)a)[c4];
        float4 b4 = ((const float4*)b)[c4];
        v.x = fmaxf(fmaf(v.x, a4.x, b4.x), 0.f);
        v.y = fmaxf(fmaf(v.y, a4.y, b4.y), 0.f);
        v.z = fmaxf(fmaf(v.z, a4.z, b4.z), 0.f);
        v.w = fmaxf(fmaf(v.w, a4.w, b4.w), 0.f);
        *(float4*)&xl[r * 132 + (c4 << 2)] = v;
    }
    __syncthreads();

    const int rg = tid >> 3;
    const int cg = tid & 7;
    const int j0 = cg * 5;
    float acc[5] = {0.f, 0.f, 0.f, 0.f, 0.f};
    for (int c = 0; c < 128; c += 4) {
        float4 xv = *(const float4*)&xl[rg * 132 + c];
        #pragma unroll
        for (int j = 0; j < 5; ++j) {
            float4 wv = *(const float4*)&wt[(j0 + j) * 132 + c];
            acc[j] = fmaf(xv.x, wv.x, acc[j]);
            acc[j] = fmaf(xv.y, wv.y, acc[j]);
            acc[j] = fmaf(xv.z, wv.z, acc[j]);
            acc[j] = fmaf(xv.w, wv.w, acc[j]);
        }
    }
    int gr = row0 + rg;
    if (gr < n) {
        #pragma unroll
        for (int j = 0; j < 5; ++j)
            OUT[(size_t)gr * 40 + j0 + j] = acc[j] + bfv[j0 + j];
    }
}

// ---------------------------------------------------------------------------
extern "C" void kernel_launch(void* const* d_in, const int* in_sizes, int n_in,
                              void* d_out, int out_size, void* d_ws, size_t ws_size,
                              hipStream_t stream) {
    const float* X0      = (const float*)d_in[0];
    const int*   edgesrc = (const int*)d_in[1];
    const int*   edgedst = (const int*)d_in[2];
    const float* bn0g = (const float*)d_in[3];
    const float* bn0b = (const float*)d_in[4];
    const float* W1   = (const float*)d_in[5];
    const float* bn1g = (const float*)d_in[7];
    const float* bn1b = (const float*)d_in[8];
    const float* W2   = (const float*)d_in[9];
    const float* bn2g = (const float*)d_in[11];
    const float* bn2b = (const float*)d_in[12];
    const float* Wf   = (const float*)d_in[13];
    const float* bfv  = (const float*)d_in[14];

    const int n = in_sizes[0] / 128;
    const int e = in_sizes[1];
    float* OUT = (float*)d_out;

    const int aggBlocks = (n + 3) / 4;               // one wave per node

    // workspace layout
    ushort* H    = (ushort*)d_ws;                     // n*128 bf16
    float*  AGG  = (float*)(H + (size_t)n * 128);     // n*128 f32
    float*  dinv = AGG + (size_t)n * 128;             // n
    int2*   ep   = (int2*)(dinv + n);                 // e
    ushort* Wswz = (ushort*)(ep + e);                 // 2 * 16384 bf16
    int*    cnt  = (int*)(Wswz + 2 * 16384);          // n
    int*    rs   = cnt + n;                           // n+1
    int*    rank = rs + n + 1;                        // e
    int*    bsum = rank + e;                          // 64
    float*  part = (float*)(bsum + 64);               // aggBlocks*256 (12.8MB)
    float* part2 = part + (size_t)aggBlocks * 256;    // 64*256
    float* a0 = part2 + 64 * 256;       float* b0 = a0 + 128;
    float* a1 = b0 + 128;               float* b1 = a1 + 128;
    float* a2 = b1 + 128;               float* b2 = a2 + 128;

    const float invn = 1.f / (float)n;
    const int nb = (n + 1023) / 1024;

    // fused: W swizzle + cnt zero (replaces hipMemsetAsync — r7: 41 us fill!)
    k_init<<<80, 256, 0, stream>>>(W1, W2, Wswz, cnt, n);

    // CSR build
    k_count<<<(e + 255) / 256, 256, 0, stream>>>(edgedst, e, cnt, rank);
    k_scanA<<<nb, 1024, 0, stream>>>(cnt, n, rs, bsum);
    k_scanC<<<(n + 255) / 256, 256, 0, stream>>>(rs, bsum, cnt, dinv, n, e);
    k_fill<<<(e + 255) / 256, 256, 0, stream>>>(edgesrc, edgedst, e, rs, rank,
                                                dinv, ep);

    const int gemmBlocks = (n + 63) / 64;

    // layer 1
    k_colstats<<<CS_BLOCKS, 256, 0, stream>>>(X0, n, part);
    k_bnfinal<<<1, 1024, 0, stream>>>(part, CS_BLOCKS, bn0g, bn0b, invn, a0, b0);
    k_gemm_mfma<<<gemmBlocks, 256, 0, stream>>>(X0, Wswz, a0, b0, 0, H, n);
    k_aggregate<<<aggBlocks, 256, 0, stream>>>(H, rs, ep, dinv, AGG, part, n);

    // layer 2 (stats of AGG came fused from aggregate)
    k_redA<<<64, 256, 0, stream>>>(part, part2, aggBlocks);
    k_bnfinal<<<1, 1024, 0, stream>>>(part2, 64, bn1g, bn1b, invn, a1, b1);
    k_gemm_mfma<<<gemmBlocks, 256, 0, stream>>>(AGG, Wswz + 16384, a1, b1, 1, H, n);
    k_aggregate<<<aggBlocks, 256, 0, stream>>>(H, rs, ep, dinv, AGG, part, n);

    // head
    k_redA<<<64, 256, 0, stream>>>(part, part2, aggBlocks);
    k_bnfinal<<<1, 1024, 0, stream>>>(part2, 64, bn2g, bn2b, invn, a2, b2);
    k_gemm_out<<<(n + 31) / 32, 256, 0, stream>>>(AGG, Wf, bfv, a2, b2, OUT, n);
}

// Round 9
// 244.510 us; speedup vs baseline: 1.0503x; 1.0284x over previous
//
#include <hip/hip_runtime.h>
#include <cstdint>
#include <cstddef>

// ---------------------------------------------------------------------------
// GCN: out = relu(BN2(A' relu(BN1(A' BN0(X) W1)) W2)) Wf + bf
// A' = D^-1/2 (A+I) D^-1/2 via per-call CSR (sorted by dst).
// Conv biases b1,b2 cancel inside the following BatchNorm and are skipped.
// BN affine (a,b per column) is fused into GEMM X-staging.
// GEMMs 128x128 use bf16 MFMA (16x16x32); hidden H stored bf16 (halves the
// random-gather traffic). AGG kept fp32.
// BN1/BN2 stats FUSED into k_aggregate (one wave per node; r6: grid-stride
// dropped occupancy 65->37% from load imbalance).
// r9: aggregate gathers TWO EDGES PER INSTRUCTION — half-waves process edge
// i / i+1 of the same node at 8B/lane (dwordx2), combined via shfl_xor(32).
// No hipMemsetAsync (r7/r8), no float atomics / no threadfence (r3).
// ---------------------------------------------------------------------------

#define CS_BLOCKS 512

typedef short s8v __attribute__((ext_vector_type(8)));
typedef float f4v __attribute__((ext_vector_type(4)));

__device__ inline ushort f2bf(float f) {            // RNE float->bf16
    uint u = __float_as_uint(f);
    return (ushort)((u + 0x7fffu + ((u >> 16) & 1u)) >> 16);
}
__device__ inline float2 bf2f2(uint u) {            // packed 2xbf16 -> 2xf32
    float2 r;
    r.x = __uint_as_float(u << 16);
    r.y = __uint_as_float(u & 0xffff0000u);
    return r;
}

// ---- fused prologue: colstats(X0) + W frag-swizzle + cnt zero -------------
// blocks 0..511: column partials of X0; 512..527: W1/W2 swizzle; 528..591:
// zero cnt[n].
__global__ __launch_bounds__(256) void k_prolog(const float* __restrict__ X,
                                                int n, float* __restrict__ part,
                                                const float* __restrict__ W1,
                                                const float* __restrict__ W2,
                                                ushort* __restrict__ Wswz,
                                                int* __restrict__ cnt) {
    const int bid = blockIdx.x;
    if (bid < CS_BLOCKS) {
        __shared__ float ls[8 * 128];
        __shared__ float lq[8 * 128];
        const int c4    = threadIdx.x & 31;
        const int rslot = threadIdx.x >> 5;
        float4 s4 = make_float4(0.f, 0.f, 0.f, 0.f);
        float4 q4 = make_float4(0.f, 0.f, 0.f, 0.f);
        const float4* X4 = (const float4*)X;
        for (int r = bid * 8 + rslot; r < n; r += CS_BLOCKS * 8) {
            float4 v = X4[(size_t)r * 32 + c4];
            s4.x += v.x; s4.y += v.y; s4.z += v.z; s4.w += v.w;
            q4.x = fmaf(v.x, v.x, q4.x); q4.y = fmaf(v.y, v.y, q4.y);
            q4.z = fmaf(v.z, v.z, q4.z); q4.w = fmaf(v.w, v.w, q4.w);
        }
        *(float4*)&ls[rslot * 128 + c4 * 4] = s4;
        *(float4*)&lq[rslot * 128 + c4 * 4] = q4;
        __syncthreads();
        float t = 0.f;
        if (threadIdx.x < 128) {
            int c = threadIdx.x;
            #pragma unroll
            for (int k = 0; k < 8; ++k) t += ls[k * 128 + c];
        } else {
            int c = threadIdx.x - 128;
            #pragma unroll
            for (int k = 0; k < 8; ++k) t += lq[k * 128 + c];
        }
        part[bid * 256 + threadIdx.x] = t;
    } else if (bid < CS_BLOCKS + 16) {
        // W frag-swizzle: frag fi = ct*4+ks; lane l holds
        // W[k=32*ks+8*(l>>4)+j][c=16*ct+(l&15)], j=0..7.
        const int wb = bid - CS_BLOCKS;
        const float* W = (wb < 8) ? W1 : W2;
        ushort* out = Wswz + (wb < 8 ? 0 : 16384);
        int t  = (wb & 7) * 256 + threadIdx.x;    // 0..2047
        int l  = t & 63;
        int fi = t >> 6;
        int ks = fi & 3, ct = fi >> 2;
        int c  = ct * 16 + (l & 15);
        int k0 = ks * 32 + ((l >> 4) << 3);
        ushort o[8];
        #pragma unroll
        for (int j = 0; j < 8; ++j)
            o[j] = f2bf(W[(size_t)(k0 + j) * 128 + c]);
        ushort4* dst = (ushort4*)(out + (size_t)t * 8);
        dst[0] = make_ushort4(o[0], o[1], o[2], o[3]);
        dst[1] = make_ushort4(o[4], o[5], o[6], o[7]);
    } else {
        const int zb = bid - CS_BLOCKS - 16;      // 0..63
        const int nv = n >> 2;
        int4* c4p = (int4*)cnt;
        const int4 z = make_int4(0, 0, 0, 0);
        for (int i = zb * 256 + threadIdx.x; i < nv; i += 64 * 256)
            c4p[i] = z;
        int i = (nv << 2) + zb * 256 + threadIdx.x;
        if (i < n) cnt[i] = 0;
    }
}

// ---- collapse nrows partial rows -> 64 rows (coalesced, bounds-checked) ---
__global__ __launch_bounds__(256) void k_redA(const float* __restrict__ part,
                                              float* __restrict__ part2,
                                              int nrows) {
    const int c = threadIdx.x;
    const int b = blockIdx.x;           // 64 blocks
    const int per = (nrows + 63) >> 6;
    const int r0 = b * per;
    const int r1 = min(r0 + per, nrows);
    float t0 = 0.f, t1 = 0.f;
    int r = r0;
    for (; r + 2 <= r1; r += 2) {
        t0 += part[(size_t)r * 256 + c];
        t1 += part[(size_t)(r + 1) * 256 + c];
    }
    if (r < r1) t0 += part[(size_t)r * 256 + c];
    part2[b * 256 + c] = t0 + t1;
}

// ---- reduce partial rows, emit BN affine (a,b). nrows % 16 == 0 -----------
__global__ __launch_bounds__(1024) void k_bnfinal(const float* __restrict__ part,
                                                  int nrows,
                                                  const float* __restrict__ g,
                                                  const float* __restrict__ be,
                                                  float invn,
                                                  float* __restrict__ a,
                                                  float* __restrict__ b) {
    __shared__ float sh[4][256];
    const int c = threadIdx.x & 255;
    const int q = threadIdx.x >> 8;
    const int per = nrows >> 2;
    float t = 0.f;
    for (int r = q * per; r < q * per + per; r += 4) {
        t += part[(r + 0) * 256 + c] + part[(r + 1) * 256 + c]
           + part[(r + 2) * 256 + c] + part[(r + 3) * 256 + c];
    }
    sh[q][c] = t;
    __syncthreads();
    if (threadIdx.x < 128) {
        int cc = threadIdx.x;
        float su = sh[0][cc] + sh[1][cc] + sh[2][cc] + sh[3][cc];
        float sq = sh[0][cc + 128] + sh[1][cc + 128]
                 + sh[2][cc + 128] + sh[3][cc + 128];
        float mu  = su * invn;
        float var = sq * invn - mu * mu;
        float av  = g[cc] * rsqrtf(var + 1e-5f);
        a[cc] = av;
        b[cc] = be[cc] - mu * av;
    }
}

// ---- CSR build ------------------------------------------------------------
__global__ __launch_bounds__(256) void k_count(const int* __restrict__ dst, int e,
                                               int* __restrict__ cnt,
                                               int* __restrict__ rank) {
    int i = blockIdx.x * 256 + threadIdx.x;
    if (i < e) rank[i] = atomicAdd(&cnt[dst[i]], 1);
}

__global__ __launch_bounds__(1024) void k_scanA(const int* __restrict__ cnt, int n,
                                                int* __restrict__ rs, int* __restrict__ bsum) {
    __shared__ int tmp[1024];
    int t = threadIdx.x;
    int i = blockIdx.x * 1024 + t;
    int v = (i < n) ? cnt[i] : 0;
    tmp[t] = v;
    __syncthreads();
    for (int off = 1; off < 1024; off <<= 1) {
        int x = (t >= off) ? tmp[t - off] : 0;
        __syncthreads();
        tmp[t] += x;
        __syncthreads();
    }
    if (i < n) rs[i] = tmp[t] - v;
    if (t == 1023) bsum[blockIdx.x] = tmp[t];
}

__global__ __launch_bounds__(256) void k_scanC(int* __restrict__ rs,
                                               const int* __restrict__ bsum,
                                               const int* __restrict__ cnt,
                                               float* __restrict__ dinv,
                                               int n, int e) {
    __shared__ int base;
    int chunk = (int)(blockIdx.x >> 2);
    if (threadIdx.x == 0) {
        int s = 0;
        for (int c = 0; c < chunk; ++c) s += bsum[c];
        base = s;
    }
    __syncthreads();
    int i = blockIdx.x * 256 + threadIdx.x;
    if (i < n) {
        rs[i] += base;
        dinv[i] = rsqrtf((float)(cnt[i] + 1));
    }
    if (blockIdx.x == 0 && threadIdx.x == 0) rs[n] = e;
}

__global__ __launch_bounds__(256) void k_fill(const int* __restrict__ src,
                                              const int* __restrict__ dst, int e,
                                              const int* __restrict__ rs,
                                              const int* __restrict__ rank,
                                              const float* __restrict__ dinv,
                                              int2* __restrict__ ep) {
    int i = blockIdx.x * 256 + threadIdx.x;
    if (i < e) {
        int d = dst[i], s = src[i];
        int p = rs[d] + rank[i];
        float nm = dinv[s] * dinv[d];
        ep[p] = make_int2(s, __float_as_int(nm));
    }
}

// ---- MFMA GEMM: H_bf16[n][128] = bf16( f(X) @ W ) -------------------------
__global__ __launch_bounds__(256) void k_gemm_mfma(const float* __restrict__ X,
                                                   const ushort* __restrict__ Wswz,
                                                   const float* __restrict__ av,
                                                   const float* __restrict__ bv,
                                                   int relu,
                                                   ushort* __restrict__ H, int n) {
    __shared__ ushort xb[64 * 128];   // 16 KB, swizzled: byte ^= (row&7)<<4
    const int tid  = threadIdx.x;
    const int row0 = blockIdx.x * 64;

    for (int i = tid; i < 64 * 32; i += 256) {
        int r = i >> 5, c4 = i & 31;
        int gr = row0 + r;
        float4 v = make_float4(0.f, 0.f, 0.f, 0.f);
        if (gr < n) v = ((const float4*)X)[(size_t)gr * 32 + c4];
        float4 a4 = ((const float4*)av)[c4];
        float4 b4 = ((const float4*)bv)[c4];
        v.x = fmaf(v.x, a4.x, b4.x);
        v.y = fmaf(v.y, a4.y, b4.y);
        v.z = fmaf(v.z, a4.z, b4.z);
        v.w = fmaf(v.w, a4.w, b4.w);
        if (relu) {
            v.x = fmaxf(v.x, 0.f); v.y = fmaxf(v.y, 0.f);
            v.z = fmaxf(v.z, 0.f); v.w = fmaxf(v.w, 0.f);
        }
        ushort4 pk = make_ushort4(f2bf(v.x), f2bf(v.y), f2bf(v.z), f2bf(v.w));
        int off = (r * 256 + c4 * 8) ^ ((r & 7) << 4);
        *(ushort4*)((char*)xb + off) = pk;
    }
    __syncthreads();

    const int wv = tid >> 6;
    const int l  = tid & 63;
    const int arow = wv * 16 + (l & 15);

    s8v afr[4];
    #pragma unroll
    for (int ks = 0; ks < 4; ++ks) {
        int off = (arow * 256 + ks * 64 + ((l >> 4) << 4)) ^ ((arow & 7) << 4);
        afr[ks] = *(const s8v*)((const char*)xb + off);
    }

    const s8v* wf = (const s8v*)Wswz;
    f4v acc[8];
    #pragma unroll
    for (int ct = 0; ct < 8; ++ct) {
        f4v c = {0.f, 0.f, 0.f, 0.f};
        #pragma unroll
        for (int ks = 0; ks < 4; ++ks) {
            s8v bb = wf[(ct * 4 + ks) * 64 + l];
            c = __builtin_amdgcn_mfma_f32_16x16x32_bf16(afr[ks], bb, c, 0, 0, 0);
        }
        acc[ct] = c;
    }

    const int rbase = row0 + wv * 16 + ((l >> 4) << 2);
    const int cidx  = l & 15;
    #pragma unroll
    for (int r = 0; r < 4; ++r) {
        int gr = rbase + r;
        if (gr < n) {
            #pragma unroll
            for (int ct = 0; ct < 8; ++ct)
                H[(size_t)gr * 128 + ct * 16 + cidx] = f2bf(acc[ct][r]);
        }
    }
}

// ---- aggregation: one wave per node, TWO EDGES PER INSTRUCTION ------------
// half = lane>>5 processes edge i+half; 32 lanes x 8B (dwordx2) per row.
// Final cross-half combine via shfl_xor(32); fused BN stats as before.
template<int NP>
__device__ inline void pair_batch(const ushort* __restrict__ H,
                                  const int2* __restrict__ ep,
                                  int i, int half, int sl,
                                  float& a0, float& a1, float& a2, float& a3) {
    int2 p[NP]; uint2 v[NP];
    #pragma unroll
    for (int k = 0; k < NP; ++k) p[k] = ep[i + 2 * k + half];
    #pragma unroll
    for (int k = 0; k < NP; ++k)
        v[k] = ((const uint2*)(H + (size_t)p[k].x * 128))[sl];
    #pragma unroll
    for (int k = 0; k < NP; ++k) {
        float w = __int_as_float(p[k].y);
        float2 f0 = bf2f2(v[k].x);
        float2 f1 = bf2f2(v[k].y);
        a0 = fmaf(w, f0.x, a0); a1 = fmaf(w, f0.y, a1);
        a2 = fmaf(w, f1.x, a2); a3 = fmaf(w, f1.y, a3);
    }
}

__global__ __launch_bounds__(256) void k_aggregate(const ushort* __restrict__ H,
                                                   const int* __restrict__ rs,
                                                   const int2* __restrict__ ep,
                                                   const float* __restrict__ dinv,
                                                   float* __restrict__ AGG,
                                                   float* __restrict__ part, int n) {
    __shared__ float red[4][128];
    __shared__ float redq[4][128];
    const int wv   = threadIdx.x >> 6;
    const int lane = threadIdx.x & 63;
    const int half = lane >> 5;
    const int sl   = lane & 31;
    const int node = blockIdx.x * 4 + wv;
    float a0 = 0.f, a1 = 0.f, a2 = 0.f, a3 = 0.f;

    if (node < n) {
        // self term (half 0 only; half 1 contributes 0, fixed by swap-add)
        if (half == 0) {
            float sn = dinv[node]; sn *= sn;
            uint2 sv = ((const uint2*)(H + (size_t)node * 128))[sl];
            float2 f0 = bf2f2(sv.x), f1 = bf2f2(sv.y);
            a0 = sn * f0.x; a1 = sn * f0.y;
            a2 = sn * f1.x; a3 = sn * f1.y;
        }
        int i  = rs[node];
        int i1 = rs[node + 1];
        for (; i + 16 <= i1; i += 16) pair_batch<8>(H, ep, i, half, sl, a0, a1, a2, a3);
        if (i + 8 <= i1) { pair_batch<4>(H, ep, i, half, sl, a0, a1, a2, a3); i += 8; }
        if (i + 4 <= i1) { pair_batch<2>(H, ep, i, half, sl, a0, a1, a2, a3); i += 4; }
        if (i + 2 <= i1) { pair_batch<1>(H, ep, i, half, sl, a0, a1, a2, a3); i += 2; }
        if (i < i1) {   // odd tail: half 1 loads same edge with w=0
            int2 p = ep[i];
            float w = (half == 0) ? __int_as_float(p.y) : 0.f;
            uint2 v = ((const uint2*)(H + (size_t)p.x * 128))[sl];
            float2 f0 = bf2f2(v.x), f1 = bf2f2(v.y);
            a0 = fmaf(w, f0.x, a0); a1 = fmaf(w, f0.y, a1);
            a2 = fmaf(w, f1.x, a2); a3 = fmaf(w, f1.y, a3);
        }
        // combine the two half-waves
        a0 += __shfl_xor(a0, 32);
        a1 += __shfl_xor(a1, 32);
        a2 += __shfl_xor(a2, 32);
        a3 += __shfl_xor(a3, 32);
        if (half == 0)
            ((float4*)(AGG + (size_t)node * 128))[sl] =
                make_float4(a0, a1, a2, a3);
    }

    // fused BN stats: each half-0 lane owns cols 4sl..4sl+3 of its node
    if (half == 0) {
        *(float4*)&red[wv][4 * sl]  = make_float4(a0, a1, a2, a3);
        *(float4*)&redq[wv][4 * sl] = make_float4(a0 * a0, a1 * a1,
                                                  a2 * a2, a3 * a3);
    }
    __syncthreads();
    const int t = threadIdx.x;
    if (t < 128)
        part[(size_t)blockIdx.x * 256 + t] =
            red[0][t] + red[1][t] + red[2][t] + red[3][t];
    else {
        int c = t - 128;
        part[(size_t)blockIdx.x * 256 + t] =
            redq[0][c] + redq[1][c] + redq[2][c] + redq[3][c];
    }
}

// ---- final projection: OUT = relu(a*X+b) @ Wf + bf  (128 -> 40) -----------
__global__ __launch_bounds__(256) void k_gemm_out(const float* __restrict__ X,
                                                  const float* __restrict__ Wf,
                                                  const float* __restrict__ bfv,
                                                  const float* __restrict__ a,
                                                  const float* __restrict__ b,
                                                  float* __restrict__ OUT, int n) {
    __shared__ float xl[32 * 132];
    __shared__ float wt[40 * 132];
    const int tid = threadIdx.x;

    for (int i = tid; i < 128 * 40; i += 256) {
        int c = i / 40;
        int j = i - c * 40;
        wt[j * 132 + c] = Wf[i];
    }
    const int row0 = blockIdx.x * 32;
    for (int i = tid; i < 32 * 32; i += 256) {
        int r = i >> 5, c4 = i & 31;
        int gr = row0 + r;
        float4 v = make_float4(0.f, 0.f, 0.f, 0.f);
        if (gr < n) v = ((const float4*)X)[(size_t)gr * 32 + c4];
        float4 a4 = ((const float4*)a)[c4];
        float4 b4 = ((const float4*)b)[c4];
        v.x = fmaxf(fmaf(v.x, a4.x, b4.x), 0.f);
        v.y = fmaxf(fmaf(v.y, a4.y, b4.y), 0.f);
        v.z = fmaxf(fmaf(v.z, a4.z, b4.z), 0.f);
        v.w = fmaxf(fmaf(v.w, a4.w, b4.w), 0.f);
        *(float4*)&xl[r * 132 + (c4 << 2)] = v;
    }
    __syncthreads();

    const int rg = tid >> 3;
    const int cg = tid & 7;
    const int j0 = cg * 5;
    float acc[5] = {0.f, 0.f, 0.f, 0.f, 0.f};
    for (int c = 0; c < 128; c += 4) {
        float4 xv = *(const float4*)&xl[rg * 132 + c];
        #pragma unroll
        for (int j = 0; j < 5; ++j) {
            float4 wv = *(const float4*)&wt[(j0 + j) * 132 + c];
            acc[j] = fmaf(xv.x, wv.x, acc[j]);
            acc[j] = fmaf(xv.y, wv.y, acc[j]);
            acc[j] = fmaf(xv.z, wv.z, acc[j]);
            acc[j] = fmaf(xv.w, wv.w, acc[j]);
        }
    }
    int gr = row0 + rg;
    if (gr < n) {
        #pragma unroll
        for (int j = 0; j < 5; ++j)
            OUT[(size_t)gr * 40 + j0 + j] = acc[j] + bfv[j0 + j];
    }
}

// ---------------------------------------------------------------------------
extern "C" void kernel_launch(void* const* d_in, const int* in_sizes, int n_in,
                              void* d_out, int out_size, void* d_ws, size_t ws_size,
                              hipStream_t stream) {
    const float* X0      = (const float*)d_in[0];
    const int*   edgesrc = (const int*)d_in[1];
    const int*   edgedst = (const int*)d_in[2];
    const float* bn0g = (const float*)d_in[3];
    const float* bn0b = (const float*)d_in[4];
    const float* W1   = (const float*)d_in[5];
    const float* bn1g = (const float*)d_in[7];
    const float* bn1b = (const float*)d_in[8];
    const float* W2   = (const float*)d_in[9];
    const float* bn2g = (const float*)d_in[11];
    const float* bn2b = (const float*)d_in[12];
    const float* Wf   = (const float*)d_in[13];
    const float* bfv  = (const float*)d_in[14];

    const int n = in_sizes[0] / 128;
    const int e = in_sizes[1];
    float* OUT = (float*)d_out;

    const int aggBlocks = (n + 3) / 4;               // one wave per node

    // workspace layout
    ushort* H    = (ushort*)d_ws;                     // n*128 bf16
    float*  AGG  = (float*)(H + (size_t)n * 128);     // n*128 f32
    float*  dinv = AGG + (size_t)n * 128;             // n
    int2*   ep   = (int2*)(dinv + n);                 // e
    ushort* Wswz = (ushort*)(ep + e);                 // 2 * 16384 bf16
    int*    cnt  = (int*)(Wswz + 2 * 16384);          // n
    int*    rs   = cnt + n;                           // n+1
    int*    rank = rs + n + 1;                        // e
    int*    bsum = rank + e;                          // 64
    float*  part = (float*)(bsum + 64);               // aggBlocks*256 (12.8MB)
    float* part2 = part + (size_t)aggBlocks * 256;    // 64*256
    float* a0 = part2 + 64 * 256;       float* b0 = a0 + 128;
    float* a1 = b0 + 128;               float* b1 = a1 + 128;
    float* a2 = b1 + 128;               float* b2 = a2 + 128;

    const float invn = 1.f / (float)n;
    const int nb = (n + 1023) / 1024;

    // fused prologue: colstats(X0) + W swizzle + cnt zero
    k_prolog<<<CS_BLOCKS + 16 + 64, 256, 0, stream>>>(X0, n, part, W1, W2,
                                                      Wswz, cnt);

    // CSR build
    k_count<<<(e + 255) / 256, 256, 0, stream>>>(edgedst, e, cnt, rank);
    k_scanA<<<nb, 1024, 0, stream>>>(cnt, n, rs, bsum);
    k_scanC<<<(n + 255) / 256, 256, 0, stream>>>(rs, bsum, cnt, dinv, n, e);
    k_fill<<<(e + 255) / 256, 256, 0, stream>>>(edgesrc, edgedst, e, rs, rank,
                                                dinv, ep);

    const int gemmBlocks = (n + 63) / 64;

    // layer 1
    k_bnfinal<<<1, 1024, 0, stream>>>(part, CS_BLOCKS, bn0g, bn0b, invn, a0, b0);
    k_gemm_mfma<<<gemmBlocks, 256, 0, stream>>>(X0, Wswz, a0, b0, 0, H, n);
    k_aggregate<<<aggBlocks, 256, 0, stream>>>(H, rs, ep, dinv, AGG, part, n);

    // layer 2 (stats of AGG came fused from aggregate)
    k_redA<<<64, 256, 0, stream>>>(part, part2, aggBlocks);
    k_bnfinal<<<1, 1024, 0, stream>>>(part2, 64, bn1g, bn1b, invn, a1, b1);
    k_gemm_mfma<<<gemmBlocks, 256, 0, stream>>>(AGG, Wswz + 16384, a1, b1, 1, H, n);
    k_aggregate<<<aggBlocks, 256, 0, stream>>>(H, rs, ep, dinv, AGG, part, n);

    // head
    k_redA<<<64, 256, 0, stream>>>(part, part2, aggBlocks);
    k_bnfinal<<<1, 1024, 0, stream>>>(part2, 64, bn2g, bn2b, invn, a2, b2);
    k_gemm_out<<<(n + 31) / 32, 256, 0, stream>>>(AGG, Wf, bfv, a2, b2, OUT, n);
}

// Round 10
// 239.694 us; speedup vs baseline: 1.0714x; 1.0201x over previous
//
#include <hip/hip_runtime.h>
#include <cstdint>
#include <cstddef>

// ---------------------------------------------------------------------------
// GCN: out = relu(BN2(A' relu(BN1(A' BN0(X) W1)) W2)) Wf + bf
// A' = D^-1/2 (A+I) D^-1/2 via per-call CSR (sorted by dst).
// Conv biases b1,b2 cancel inside the following BatchNorm and are skipped.
// BN affine (a,b) folded into each GEMM block (computed from 64-row part2 —
// k_bnfinal dispatches deleted, r10). GEMMs use bf16 MFMA 16x16x32; H bf16.
// Aggregate: one wave per node, FOUR edges per gather instr (quarter-waves,
// dwordx4), combined via shfl_xor(16/32); fused BN stats (r6/r9 lessons:
// max wave count + max edges-in-flight win for the latency-bound gather).
// No hipMemsetAsync (r7), no float atomics / no threadfence (r3).
// ---------------------------------------------------------------------------

#define CS_BLOCKS 512

typedef short s8v __attribute__((ext_vector_type(8)));
typedef float f4v __attribute__((ext_vector_type(4)));

__device__ inline ushort f2bf(float f) {            // RNE float->bf16
    uint u = __float_as_uint(f);
    return (ushort)((u + 0x7fffu + ((u >> 16) & 1u)) >> 16);
}
__device__ inline float2 bf2f2(uint u) {            // packed 2xbf16 -> 2xf32
    float2 r;
    r.x = __uint_as_float(u << 16);
    r.y = __uint_as_float(u & 0xffff0000u);
    return r;
}

// ---- fused prologue: colstats(X0) + W frag-swizzle + cnt zero -------------
__global__ __launch_bounds__(256) void k_prolog(const float* __restrict__ X,
                                                int n, float* __restrict__ part,
                                                const float* __restrict__ W1,
                                                const float* __restrict__ W2,
                                                ushort* __restrict__ Wswz,
                                                int* __restrict__ cnt) {
    const int bid = blockIdx.x;
    if (bid < CS_BLOCKS) {
        __shared__ float ls[8 * 128];
        __shared__ float lq[8 * 128];
        const int c4    = threadIdx.x & 31;
        const int rslot = threadIdx.x >> 5;
        float4 s4 = make_float4(0.f, 0.f, 0.f, 0.f);
        float4 q4 = make_float4(0.f, 0.f, 0.f, 0.f);
        const float4* X4 = (const float4*)X;
        for (int r = bid * 8 + rslot; r < n; r += CS_BLOCKS * 8) {
            float4 v = X4[(size_t)r * 32 + c4];
            s4.x += v.x; s4.y += v.y; s4.z += v.z; s4.w += v.w;
            q4.x = fmaf(v.x, v.x, q4.x); q4.y = fmaf(v.y, v.y, q4.y);
            q4.z = fmaf(v.z, v.z, q4.z); q4.w = fmaf(v.w, v.w, q4.w);
        }
        *(float4*)&ls[rslot * 128 + c4 * 4] = s4;
        *(float4*)&lq[rslot * 128 + c4 * 4] = q4;
        __syncthreads();
        float t = 0.f;
        if (threadIdx.x < 128) {
            int c = threadIdx.x;
            #pragma unroll
            for (int k = 0; k < 8; ++k) t += ls[k * 128 + c];
        } else {
            int c = threadIdx.x - 128;
            #pragma unroll
            for (int k = 0; k < 8; ++k) t += lq[k * 128 + c];
        }
        part[bid * 256 + threadIdx.x] = t;
    } else if (bid < CS_BLOCKS + 16) {
        const int wb = bid - CS_BLOCKS;
        const float* W = (wb < 8) ? W1 : W2;
        ushort* out = Wswz + (wb < 8 ? 0 : 16384);
        int t  = (wb & 7) * 256 + threadIdx.x;    // 0..2047
        int l  = t & 63;
        int fi = t >> 6;
        int ks = fi & 3, ct = fi >> 2;
        int c  = ct * 16 + (l & 15);
        int k0 = ks * 32 + ((l >> 4) << 3);
        ushort o[8];
        #pragma unroll
        for (int j = 0; j < 8; ++j)
            o[j] = f2bf(W[(size_t)(k0 + j) * 128 + c]);
        ushort4* dst = (ushort4*)(out + (size_t)t * 8);
        dst[0] = make_ushort4(o[0], o[1], o[2], o[3]);
        dst[1] = make_ushort4(o[4], o[5], o[6], o[7]);
    } else {
        const int zb = bid - CS_BLOCKS - 16;      // 0..63
        const int nv = n >> 2;
        int4* c4p = (int4*)cnt;
        const int4 z = make_int4(0, 0, 0, 0);
        for (int i = zb * 256 + threadIdx.x; i < nv; i += 64 * 256)
            c4p[i] = z;
        int i = (nv << 2) + zb * 256 + threadIdx.x;
        if (i < n) cnt[i] = 0;
    }
}

// ---- collapse nrows partial rows -> 64 rows (coalesced, bounds-checked) ---
__global__ __launch_bounds__(256) void k_redA(const float* __restrict__ part,
                                              float* __restrict__ part2,
                                              int nrows) {
    const int c = threadIdx.x;
    const int b = blockIdx.x;           // 64 blocks
    const int per = (nrows + 63) >> 6;
    const int r0 = b * per;
    const int r1 = min(r0 + per, nrows);
    float t0 = 0.f, t1 = 0.f;
    int r = r0;
    for (; r + 2 <= r1; r += 2) {
        t0 += part[(size_t)r * 256 + c];
        t1 += part[(size_t)(r + 1) * 256 + c];
    }
    if (r < r1) t0 += part[(size_t)r * 256 + c];
    part2[b * 256 + c] = t0 + t1;
}

// ---- in-block BN finalize from part2 (64 rows x 256) ----------------------
// Writes affine (a,b) into LDS buffers. Requires 256 threads.
__device__ inline void bn_inblock(const float* __restrict__ part2,
                                  const float* __restrict__ g,
                                  const float* __restrict__ be,
                                  float invn, float* __restrict__ tmp,
                                  float* __restrict__ abuf,
                                  float* __restrict__ bbuf) {
    const int tid = threadIdx.x;
    float t = 0.f;
    #pragma unroll 8
    for (int r = 0; r < 64; ++r) t += part2[r * 256 + tid];
    tmp[tid] = t;
    __syncthreads();
    if (tid < 128) {
        float mu  = tmp[tid] * invn;
        float var = tmp[tid + 128] * invn - mu * mu;
        float av  = g[tid] * rsqrtf(var + 1e-5f);
        abuf[tid] = av;
        bbuf[tid] = be[tid] - mu * av;
    }
    __syncthreads();
}

// ---- CSR build ------------------------------------------------------------
__global__ __launch_bounds__(256) void k_count(const int* __restrict__ dst, int e,
                                               int* __restrict__ cnt,
                                               int* __restrict__ rank) {
    int i = blockIdx.x * 256 + threadIdx.x;
    if (i < e) rank[i] = atomicAdd(&cnt[dst[i]], 1);
}

__global__ __launch_bounds__(1024) void k_scanA(const int* __restrict__ cnt, int n,
                                                int* __restrict__ rs, int* __restrict__ bsum) {
    __shared__ int tmp[1024];
    int t = threadIdx.x;
    int i = blockIdx.x * 1024 + t;
    int v = (i < n) ? cnt[i] : 0;
    tmp[t] = v;
    __syncthreads();
    for (int off = 1; off < 1024; off <<= 1) {
        int x = (t >= off) ? tmp[t - off] : 0;
        __syncthreads();
        tmp[t] += x;
        __syncthreads();
    }
    if (i < n) rs[i] = tmp[t] - v;
    if (t == 1023) bsum[blockIdx.x] = tmp[t];
}

__global__ __launch_bounds__(256) void k_scanC(int* __restrict__ rs,
                                               const int* __restrict__ bsum,
                                               const int* __restrict__ cnt,
                                               float* __restrict__ dinv,
                                               int n, int e) {
    __shared__ int base;
    int chunk = (int)(blockIdx.x >> 2);
    if (threadIdx.x == 0) {
        int s = 0;
        for (int c = 0; c < chunk; ++c) s += bsum[c];
        base = s;
    }
    __syncthreads();
    int i = blockIdx.x * 256 + threadIdx.x;
    if (i < n) {
        rs[i] += base;
        dinv[i] = rsqrtf((float)(cnt[i] + 1));
    }
    if (blockIdx.x == 0 && threadIdx.x == 0) rs[n] = e;
}

__global__ __launch_bounds__(256) void k_fill(const int* __restrict__ src,
                                              const int* __restrict__ dst, int e,
                                              const int* __restrict__ rs,
                                              const int* __restrict__ rank,
                                              const float* __restrict__ dinv,
                                              int2* __restrict__ ep) {
    int i = blockIdx.x * 256 + threadIdx.x;
    if (i < e) {
        int d = dst[i], s = src[i];
        int p = rs[d] + rank[i];
        float nm = dinv[s] * dinv[d];
        ep[p] = make_int2(s, __float_as_int(nm));
    }
}

// ---- MFMA GEMM: H_bf16[n][128] = bf16( f(X) @ W ), BN folded in-block -----
__global__ __launch_bounds__(256) void k_gemm_mfma(const float* __restrict__ X,
                                                   const ushort* __restrict__ Wswz,
                                                   const float* __restrict__ part2,
                                                   const float* __restrict__ g,
                                                   const float* __restrict__ be,
                                                   float invn, int relu,
                                                   ushort* __restrict__ H, int n) {
    __shared__ ushort xb[64 * 128];   // 16 KB, swizzled: byte ^= (row&7)<<4
    __shared__ float tmp[256];
    __shared__ float abuf[128], bbuf[128];
    const int tid  = threadIdx.x;
    const int row0 = blockIdx.x * 64;

    bn_inblock(part2, g, be, invn, tmp, abuf, bbuf);

    for (int i = tid; i < 64 * 32; i += 256) {
        int r = i >> 5, c4 = i & 31;
        int gr = row0 + r;
        float4 v = make_float4(0.f, 0.f, 0.f, 0.f);
        if (gr < n) v = ((const float4*)X)[(size_t)gr * 32 + c4];
        float4 a4 = *(const float4*)&abuf[c4 * 4];
        float4 b4 = *(const float4*)&bbuf[c4 * 4];
        v.x = fmaf(v.x, a4.x, b4.x);
        v.y = fmaf(v.y, a4.y, b4.y);
        v.z = fmaf(v.z, a4.z, b4.z);
        v.w = fmaf(v.w, a4.w, b4.w);
        if (relu) {
            v.x = fmaxf(v.x, 0.f); v.y = fmaxf(v.y, 0.f);
            v.z = fmaxf(v.z, 0.f); v.w = fmaxf(v.w, 0.f);
        }
        ushort4 pk = make_ushort4(f2bf(v.x), f2bf(v.y), f2bf(v.z), f2bf(v.w));
        int off = (r * 256 + c4 * 8) ^ ((r & 7) << 4);
        *(ushort4*)((char*)xb + off) = pk;
    }
    __syncthreads();

    const int wv = tid >> 6;
    const int l  = tid & 63;
    const int arow = wv * 16 + (l & 15);

    s8v afr[4];
    #pragma unroll
    for (int ks = 0; ks < 4; ++ks) {
        int off = (arow * 256 + ks * 64 + ((l >> 4) << 4)) ^ ((arow & 7) << 4);
        afr[ks] = *(const s8v*)((const char*)xb + off);
    }

    const s8v* wf = (const s8v*)Wswz;
    f4v acc[8];
    #pragma unroll
    for (int ct = 0; ct < 8; ++ct) {
        f4v c = {0.f, 0.f, 0.f, 0.f};
        #pragma unroll
        for (int ks = 0; ks < 4; ++ks) {
            s8v bb = wf[(ct * 4 + ks) * 64 + l];
            c = __builtin_amdgcn_mfma_f32_16x16x32_bf16(afr[ks], bb, c, 0, 0, 0);
        }
        acc[ct] = c;
    }

    const int rbase = row0 + wv * 16 + ((l >> 4) << 2);
    const int cidx  = l & 15;
    #pragma unroll
    for (int r = 0; r < 4; ++r) {
        int gr = rbase + r;
        if (gr < n) {
            #pragma unroll
            for (int ct = 0; ct < 8; ++ct)
                H[(size_t)gr * 128 + ct * 16 + cidx] = f2bf(acc[ct][r]);
        }
    }
}

// ---- aggregation: one wave per node, FOUR EDGES PER INSTRUCTION -----------
// quarter q = lane>>4 processes edge i+q; 16 lanes x 16B (dwordx4) per row.
// Combine via shfl_xor(16) + shfl_xor(32); fused BN stats.
template<int NP>
__device__ inline void quad_batch(const ushort* __restrict__ H,
                                  const int2* __restrict__ ep,
                                  int i, int q, int sl, float* __restrict__ a) {
    int2 p[NP]; uint4 v[NP];
    #pragma unroll
    for (int k = 0; k < NP; ++k) p[k] = ep[i + 4 * k + q];
    #pragma unroll
    for (int k = 0; k < NP; ++k)
        v[k] = ((const uint4*)(H + (size_t)p[k].x * 128))[sl];
    #pragma unroll
    for (int k = 0; k < NP; ++k) {
        float w = __int_as_float(p[k].y);
        float2 f0 = bf2f2(v[k].x), f1 = bf2f2(v[k].y);
        float2 f2 = bf2f2(v[k].z), f3 = bf2f2(v[k].w);
        a[0] = fmaf(w, f0.x, a[0]); a[1] = fmaf(w, f0.y, a[1]);
        a[2] = fmaf(w, f1.x, a[2]); a[3] = fmaf(w, f1.y, a[3]);
        a[4] = fmaf(w, f2.x, a[4]); a[5] = fmaf(w, f2.y, a[5]);
        a[6] = fmaf(w, f3.x, a[6]); a[7] = fmaf(w, f3.y, a[7]);
    }
}

__global__ __launch_bounds__(256) void k_aggregate(const ushort* __restrict__ H,
                                                   const int* __restrict__ rs,
                                                   const int2* __restrict__ ep,
                                                   const float* __restrict__ dinv,
                                                   float* __restrict__ AGG,
                                                   float* __restrict__ part, int n) {
    __shared__ float red[4][128];
    __shared__ float redq[4][128];
    const int wv   = threadIdx.x >> 6;
    const int lane = threadIdx.x & 63;
    const int q    = lane >> 4;      // quarter 0..3
    const int sl   = lane & 15;      // 16 lanes x 16B per row
    const int node = blockIdx.x * 4 + wv;
    float a[8] = {0.f, 0.f, 0.f, 0.f, 0.f, 0.f, 0.f, 0.f};

    if (node < n) {
        if (q == 0) {   // self term on quarter 0 only
            float sn = dinv[node]; sn *= sn;
            uint4 sv = ((const uint4*)(H + (size_t)node * 128))[sl];
            float2 f0 = bf2f2(sv.x), f1 = bf2f2(sv.y);
            float2 f2 = bf2f2(sv.z), f3 = bf2f2(sv.w);
            a[0] = sn * f0.x; a[1] = sn * f0.y;
            a[2] = sn * f1.x; a[3] = sn * f1.y;
            a[4] = sn * f2.x; a[5] = sn * f2.y;
            a[6] = sn * f3.x; a[7] = sn * f3.y;
        }
        int i  = rs[node];
        int i1 = rs[node + 1];
        for (; i + 16 <= i1; i += 16) quad_batch<4>(H, ep, i, q, sl, a);
        if (i + 8 <= i1) { quad_batch<2>(H, ep, i, q, sl, a); i += 8; }
        if (i + 4 <= i1) { quad_batch<1>(H, ep, i, q, sl, a); i += 4; }
        if (i < i1) {   // 1..3 leftover: inactive quarters use w=0
            int idx = min(i + q, i1 - 1);
            int2 p = ep[idx];
            float w = (i + q < i1) ? __int_as_float(p.y) : 0.f;
            uint4 v = ((const uint4*)(H + (size_t)p.x * 128))[sl];
            float2 f0 = bf2f2(v.x), f1 = bf2f2(v.y);
            float2 f2 = bf2f2(v.z), f3 = bf2f2(v.w);
            a[0] = fmaf(w, f0.x, a[0]); a[1] = fmaf(w, f0.y, a[1]);
            a[2] = fmaf(w, f1.x, a[2]); a[3] = fmaf(w, f1.y, a[3]);
            a[4] = fmaf(w, f2.x, a[4]); a[5] = fmaf(w, f2.y, a[5]);
            a[6] = fmaf(w, f3.x, a[6]); a[7] = fmaf(w, f3.y, a[7]);
        }
        #pragma unroll
        for (int j = 0; j < 8; ++j) {
            a[j] += __shfl_xor(a[j], 16);
            a[j] += __shfl_xor(a[j], 32);
        }
        if (q == 0) {
            float4* dst = (float4*)(AGG + (size_t)node * 128);
            dst[2 * sl]     = make_float4(a[0], a[1], a[2], a[3]);
            dst[2 * sl + 1] = make_float4(a[4], a[5], a[6], a[7]);
        }
    }

    // fused BN stats: quarter-0 lanes own cols 8sl..8sl+7 of their node
    if (q == 0) {
        *(float4*)&red[wv][8 * sl]      = make_float4(a[0], a[1], a[2], a[3]);
        *(float4*)&red[wv][8 * sl + 4]  = make_float4(a[4], a[5], a[6], a[7]);
        *(float4*)&redq[wv][8 * sl]     = make_float4(a[0] * a[0], a[1] * a[1],
                                                      a[2] * a[2], a[3] * a[3]);
        *(float4*)&redq[wv][8 * sl + 4] = make_float4(a[4] * a[4], a[5] * a[5],
                                                      a[6] * a[6], a[7] * a[7]);
    } else if (node >= n) {
        // nothing: red rows for missing nodes must still be zero — handled
        // below by the fact that a[] stayed zero only on q==0 writes; for
        // out-of-range nodes q==0 writes zeros (a[] untouched).
    }
    if (q == 0 && node >= n) {
        *(float4*)&red[wv][8 * sl]      = make_float4(0.f, 0.f, 0.f, 0.f);
        *(float4*)&red[wv][8 * sl + 4]  = make_float4(0.f, 0.f, 0.f, 0.f);
        *(float4*)&redq[wv][8 * sl]     = make_float4(0.f, 0.f, 0.f, 0.f);
        *(float4*)&redq[wv][8 * sl + 4] = make_float4(0.f, 0.f, 0.f, 0.f);
    }
    __syncthreads();
    const int t = threadIdx.x;
    if (t < 128)
        part[(size_t)blockIdx.x * 256 + t] =
            red[0][t] + red[1][t] + red[2][t] + red[3][t];
    else {
        int c = t - 128;
        part[(size_t)blockIdx.x * 256 + t] =
            redq[0][c] + redq[1][c] + redq[2][c] + redq[3][c];
    }
}

// ---- final projection: OUT = relu(a*X+b) @ Wf + bf, BN folded in-block ----
__global__ __launch_bounds__(256) void k_gemm_out(const float* __restrict__ X,
                                                  const float* __restrict__ Wf,
                                                  const float* __restrict__ bfv,
                                                  const float* __restrict__ part2,
                                                  const float* __restrict__ g,
                                                  const float* __restrict__ be,
                                                  float invn,
                                                  float* __restrict__ OUT, int n) {
    __shared__ float xl[32 * 132];
    __shared__ float wt[40 * 132];
    __shared__ float tmp[256];
    __shared__ float abuf[128], bbuf[128];
    const int tid = threadIdx.x;

    bn_inblock(part2, g, be, invn, tmp, abuf, bbuf);

    for (int i = tid; i < 128 * 40; i += 256) {
        int c = i / 40;
        int j = i - c * 40;
        wt[j * 132 + c] = Wf[i];
    }
    const int row0 = blockIdx.x * 32;
    for (int i = tid; i < 32 * 32; i += 256) {
        int r = i >> 5, c4 = i & 31;
        int gr = row0 + r;
        float4 v = make_float4(0.f, 0.f, 0.f, 0.f);
        if (gr < n) v = ((const float4*)X)[(size_t)gr * 32 + c4];
        float4 a4 = *(const float4*)&abuf[c4 * 4];
        float4 b4 = *(const float4*)&bbuf[c4 * 4];
        v.x = fmaxf(fmaf(v.x, a4.x, b4.x), 0.f);
        v.y = fmaxf(fmaf(v.y, a4.y, b4.y), 0.f);
        v.z = fmaxf(fmaf(v.z, a4.z, b4.z), 0.f);
        v.w = fmaxf(fmaf(v.w, a4.w, b4.w), 0.f);
        *(float4*)&xl[r * 132 + (c4 << 2)] = v;
    }
    __syncthreads();

    const int rg = tid >> 3;
    const int cg = tid & 7;
    const int j0 = cg * 5;
    float acc[5] = {0.f, 0.f, 0.f, 0.f, 0.f};
    for (int c = 0; c < 128; c += 4) {
        float4 xv = *(const float4*)&xl[rg * 132 + c];
        #pragma unroll
        for (int j = 0; j < 5; ++j) {
            float4 wv = *(const float4*)&wt[(j0 + j) * 132 + c];
            acc[j] = fmaf(xv.x, wv.x, acc[j]);
            acc[j] = fmaf(xv.y, wv.y, acc[j]);
            acc[j] = fmaf(xv.z, wv.z, acc[j]);
            acc[j] = fmaf(xv.w, wv.w, acc[j]);
        }
    }
    int gr = row0 + rg;
    if (gr < n) {
        #pragma unroll
        for (int j = 0; j < 5; ++j)
            OUT[(size_t)gr * 40 + j0 + j] = acc[j] + bfv[j0 + j];
    }
}

// ---------------------------------------------------------------------------
extern "C" void kernel_launch(void* const* d_in, const int* in_sizes, int n_in,
                              void* d_out, int out_size, void* d_ws, size_t ws_size,
                              hipStream_t stream) {
    const float* X0      = (const float*)d_in[0];
    const int*   edgesrc = (const int*)d_in[1];
    const int*   edgedst = (const int*)d_in[2];
    const float* bn0g = (const float*)d_in[3];
    const float* bn0b = (const float*)d_in[4];
    const float* W1   = (const float*)d_in[5];
    const float* bn1g = (const float*)d_in[7];
    const float* bn1b = (const float*)d_in[8];
    const float* W2   = (const float*)d_in[9];
    const float* bn2g = (const float*)d_in[11];
    const float* bn2b = (const float*)d_in[12];
    const float* Wf   = (const float*)d_in[13];
    const float* bfv  = (const float*)d_in[14];

    const int n = in_sizes[0] / 128;
    const int e = in_sizes[1];
    float* OUT = (float*)d_out;

    const int aggBlocks = (n + 3) / 4;               // one wave per node

    // workspace layout
    ushort* H    = (ushort*)d_ws;                     // n*128 bf16
    float*  AGG  = (float*)(H + (size_t)n * 128);     // n*128 f32
    float*  dinv = AGG + (size_t)n * 128;             // n
    int2*   ep   = (int2*)(dinv + n);                 // e
    ushort* Wswz = (ushort*)(ep + e);                 // 2 * 16384 bf16
    int*    cnt  = (int*)(Wswz + 2 * 16384);          // n
    int*    rs   = cnt + n;                           // n+1
    int*    rank = rs + n + 1;                        // e
    int*    bsum = rank + e;                          // 64
    float*  part = (float*)(bsum + 64);               // aggBlocks*256 (12.8MB)
    float* part2 = part + (size_t)aggBlocks * 256;    // 64*256

    const float invn = 1.f / (float)n;
    const int nb = (n + 1023) / 1024;

    // fused prologue: colstats(X0) + W swizzle + cnt zero
    k_prolog<<<CS_BLOCKS + 16 + 64, 256, 0, stream>>>(X0, n, part, W1, W2,
                                                      Wswz, cnt);

    // CSR build
    k_count<<<(e + 255) / 256, 256, 0, stream>>>(edgedst, e, cnt, rank);
    k_scanA<<<nb, 1024, 0, stream>>>(cnt, n, rs, bsum);
    k_scanC<<<(n + 255) / 256, 256, 0, stream>>>(rs, bsum, cnt, dinv, n, e);
    k_fill<<<(e + 255) / 256, 256, 0, stream>>>(edgesrc, edgedst, e, rs, rank,
                                                dinv, ep);

    const int gemmBlocks = (n + 63) / 64;

    // layer 1
    k_redA<<<64, 256, 0, stream>>>(part, part2, CS_BLOCKS);
    k_gemm_mfma<<<gemmBlocks, 256, 0, stream>>>(X0, Wswz, part2, bn0g, bn0b,
                                                invn, 0, H, n);
    k_aggregate<<<aggBlocks, 256, 0, stream>>>(H, rs, ep, dinv, AGG, part, n);

    // layer 2 (stats of AGG came fused from aggregate)
    k_redA<<<64, 256, 0, stream>>>(part, part2, aggBlocks);
    k_gemm_mfma<<<gemmBlocks, 256, 0, stream>>>(AGG, Wswz + 16384, part2, bn1g,
                                                bn1b, invn, 1, H, n);
    k_aggregate<<<aggBlocks, 256, 0, stream>>>(H, rs, ep, dinv, AGG, part, n);

    // head
    k_redA<<<64, 256, 0, stream>>>(part, part2, aggBlocks);
    k_gemm_out<<<(n + 31) / 32, 256, 0, stream>>>(AGG, Wf, bfv, part2, bn2g,
                                                  bn2b, invn, OUT, n);
}

// Round 11
// 230.600 us; speedup vs baseline: 1.1136x; 1.0394x over previous
//
#include <hip/hip_runtime.h>
#include <cstdint>
#include <cstddef>

// ---------------------------------------------------------------------------
// GCN: out = relu(BN2(A' relu(BN1(A' BN0(X) W1)) W2)) Wf + bf
// A' = D^-1/2 (A+I) D^-1/2 via per-call CSR (sorted by dst).
// Conv biases b1,b2 cancel inside the following BatchNorm and are skipped.
// BN affine folded into each GEMM block (from 64-row part2). GEMMs bf16 MFMA
// 16x16x32. H AND AGG stored bf16 (r11): halves aggregate writes + layer-2/
// head input reads; BN stats stay fp32 (computed from registers pre-round).
// Aggregate: one wave per node, 4 edges/instr (quarter-waves, dwordx4),
// combined via shfl_xor(16/32); fused BN stats (r6/r9: max waves + max
// edges-in-flight win for the latency-bound gather).
// No hipMemsetAsync (r7), no float atomics / no threadfence (r3).
// ---------------------------------------------------------------------------

#define CS_BLOCKS 512

typedef short  s8v __attribute__((ext_vector_type(8)));
typedef ushort u8v __attribute__((ext_vector_type(8)));
typedef float  f4v __attribute__((ext_vector_type(4)));

__device__ inline ushort f2bf(float f) {            // RNE float->bf16
    uint u = __float_as_uint(f);
    return (ushort)((u + 0x7fffu + ((u >> 16) & 1u)) >> 16);
}
__device__ inline float bf2f(ushort u) {
    return __uint_as_float((uint)u << 16);
}
__device__ inline float2 bf2f2(uint u) {            // packed 2xbf16 -> 2xf32
    float2 r;
    r.x = __uint_as_float(u << 16);
    r.y = __uint_as_float(u & 0xffff0000u);
    return r;
}

// ---- fused prologue: colstats(X0) + W frag-swizzle + cnt zero -------------
__global__ __launch_bounds__(256) void k_prolog(const float* __restrict__ X,
                                                int n, float* __restrict__ part,
                                                const float* __restrict__ W1,
                                                const float* __restrict__ W2,
                                                ushort* __restrict__ Wswz,
                                                int* __restrict__ cnt) {
    const int bid = blockIdx.x;
    if (bid < CS_BLOCKS) {
        __shared__ float ls[8 * 128];
        __shared__ float lq[8 * 128];
        const int c4    = threadIdx.x & 31;
        const int rslot = threadIdx.x >> 5;
        float4 s4 = make_float4(0.f, 0.f, 0.f, 0.f);
        float4 q4 = make_float4(0.f, 0.f, 0.f, 0.f);
        const float4* X4 = (const float4*)X;
        for (int r = bid * 8 + rslot; r < n; r += CS_BLOCKS * 8) {
            float4 v = X4[(size_t)r * 32 + c4];
            s4.x += v.x; s4.y += v.y; s4.z += v.z; s4.w += v.w;
            q4.x = fmaf(v.x, v.x, q4.x); q4.y = fmaf(v.y, v.y, q4.y);
            q4.z = fmaf(v.z, v.z, q4.z); q4.w = fmaf(v.w, v.w, q4.w);
        }
        *(float4*)&ls[rslot * 128 + c4 * 4] = s4;
        *(float4*)&lq[rslot * 128 + c4 * 4] = q4;
        __syncthreads();
        float t = 0.f;
        if (threadIdx.x < 128) {
            int c = threadIdx.x;
            #pragma unroll
            for (int k = 0; k < 8; ++k) t += ls[k * 128 + c];
        } else {
            int c = threadIdx.x - 128;
            #pragma unroll
            for (int k = 0; k < 8; ++k) t += lq[k * 128 + c];
        }
        part[bid * 256 + threadIdx.x] = t;
    } else if (bid < CS_BLOCKS + 16) {
        const int wb = bid - CS_BLOCKS;
        const float* W = (wb < 8) ? W1 : W2;
        ushort* out = Wswz + (wb < 8 ? 0 : 16384);
        int t  = (wb & 7) * 256 + threadIdx.x;    // 0..2047
        int l  = t & 63;
        int fi = t >> 6;
        int ks = fi & 3, ct = fi >> 2;
        int c  = ct * 16 + (l & 15);
        int k0 = ks * 32 + ((l >> 4) << 3);
        ushort o[8];
        #pragma unroll
        for (int j = 0; j < 8; ++j)
            o[j] = f2bf(W[(size_t)(k0 + j) * 128 + c]);
        ushort4* dst = (ushort4*)(out + (size_t)t * 8);
        dst[0] = make_ushort4(o[0], o[1], o[2], o[3]);
        dst[1] = make_ushort4(o[4], o[5], o[6], o[7]);
    } else {
        const int zb = bid - CS_BLOCKS - 16;      // 0..63
        const int nv = n >> 2;
        int4* c4p = (int4*)cnt;
        const int4 z = make_int4(0, 0, 0, 0);
        for (int i = zb * 256 + threadIdx.x; i < nv; i += 64 * 256)
            c4p[i] = z;
        int i = (nv << 2) + zb * 256 + threadIdx.x;
        if (i < n) cnt[i] = 0;
    }
}

// ---- collapse nrows partial rows -> 64 rows (role-shared helper) ----------
__device__ inline void redA_body(const float* __restrict__ part,
                                 float* __restrict__ part2,
                                 int nrows, int b) {
    const int c = threadIdx.x;
    const int per = (nrows + 63) >> 6;
    const int r0 = b * per;
    const int r1 = min(r0 + per, nrows);
    float t0 = 0.f, t1 = 0.f;
    int r = r0;
    for (; r + 2 <= r1; r += 2) {
        t0 += part[(size_t)r * 256 + c];
        t1 += part[(size_t)(r + 1) * 256 + c];
    }
    if (r < r1) t0 += part[(size_t)r * 256 + c];
    part2[b * 256 + c] = t0 + t1;
}

__global__ __launch_bounds__(256) void k_redA(const float* __restrict__ part,
                                              float* __restrict__ part2,
                                              int nrows) {
    redA_body(part, part2, nrows, blockIdx.x);
}

// ---- in-block BN finalize from part2 (64 rows x 256) ----------------------
__device__ inline void bn_inblock(const float* __restrict__ part2,
                                  const float* __restrict__ g,
                                  const float* __restrict__ be,
                                  float invn, float* __restrict__ tmp,
                                  float* __restrict__ abuf,
                                  float* __restrict__ bbuf) {
    const int tid = threadIdx.x;
    float t = 0.f;
    #pragma unroll 8
    for (int r = 0; r < 64; ++r) t += part2[r * 256 + tid];
    tmp[tid] = t;
    __syncthreads();
    if (tid < 128) {
        float mu  = tmp[tid] * invn;
        float var = tmp[tid + 128] * invn - mu * mu;
        float av  = g[tid] * rsqrtf(var + 1e-5f);
        abuf[tid] = av;
        bbuf[tid] = be[tid] - mu * av;
    }
    __syncthreads();
}

// ---- CSR build ------------------------------------------------------------
__global__ __launch_bounds__(256) void k_count(const int* __restrict__ dst, int e,
                                               int* __restrict__ cnt,
                                               int* __restrict__ rank) {
    int i = blockIdx.x * 256 + threadIdx.x;
    if (i < e) rank[i] = atomicAdd(&cnt[dst[i]], 1);
}

__global__ __launch_bounds__(1024) void k_scanA(const int* __restrict__ cnt, int n,
                                                int* __restrict__ rs, int* __restrict__ bsum) {
    __shared__ int tmp[1024];
    int t = threadIdx.x;
    int i = blockIdx.x * 1024 + t;
    int v = (i < n) ? cnt[i] : 0;
    tmp[t] = v;
    __syncthreads();
    for (int off = 1; off < 1024; off <<= 1) {
        int x = (t >= off) ? tmp[t - off] : 0;
        __syncthreads();
        tmp[t] += x;
        __syncthreads();
    }
    if (i < n) rs[i] = tmp[t] - v;
    if (t == 1023) bsum[blockIdx.x] = tmp[t];
}

__global__ __launch_bounds__(256) void k_scanC(int* __restrict__ rs,
                                               const int* __restrict__ bsum,
                                               const int* __restrict__ cnt,
                                               float* __restrict__ dinv,
                                               int n, int e) {
    __shared__ int base;
    int chunk = (int)(blockIdx.x >> 2);
    if (threadIdx.x == 0) {
        int s = 0;
        for (int c = 0; c < chunk; ++c) s += bsum[c];
        base = s;
    }
    __syncthreads();
    int i = blockIdx.x * 256 + threadIdx.x;
    if (i < n) {
        rs[i] += base;
        dinv[i] = rsqrtf((float)(cnt[i] + 1));
    }
    if (blockIdx.x == 0 && threadIdx.x == 0) rs[n] = e;
}

// fill + layer-1 redA fused (independent roles, r11: one fewer dispatch)
__global__ __launch_bounds__(256) void k_fill(const int* __restrict__ src,
                                              const int* __restrict__ dst, int e,
                                              const int* __restrict__ rs,
                                              const int* __restrict__ rank,
                                              const float* __restrict__ dinv,
                                              int2* __restrict__ ep,
                                              const float* __restrict__ part,
                                              float* __restrict__ part2,
                                              int fillBlocks) {
    const int bid = blockIdx.x;
    if (bid < fillBlocks) {
        int i = bid * 256 + threadIdx.x;
        if (i < e) {
            int d = dst[i], s = src[i];
            int p = rs[d] + rank[i];
            float nm = dinv[s] * dinv[d];
            ep[p] = make_int2(s, __float_as_int(nm));
        }
    } else {
        redA_body(part, part2, CS_BLOCKS, bid - fillBlocks);
    }
}

// ---- MFMA GEMM: H_bf16[n][128] = bf16( f(X) @ W ), BN folded in-block -----
// BF16IN: X is bf16 (layer 2); else fp32 (layer 1).
template<int BF16IN>
__global__ __launch_bounds__(256) void k_gemm_mfma(const void* __restrict__ Xv,
                                                   const ushort* __restrict__ Wswz,
                                                   const float* __restrict__ part2,
                                                   const float* __restrict__ g,
                                                   const float* __restrict__ be,
                                                   float invn, int relu,
                                                   ushort* __restrict__ H, int n) {
    __shared__ ushort xb[64 * 128];   // 16 KB, swizzled: byte ^= (row&7)<<4
    __shared__ float tmp[256];
    __shared__ float abuf[128], bbuf[128];
    const int tid  = threadIdx.x;
    const int row0 = blockIdx.x * 64;

    bn_inblock(part2, g, be, invn, tmp, abuf, bbuf);

    if (BF16IN) {
        const ushort* X = (const ushort*)Xv;
        for (int i = tid; i < 64 * 16; i += 256) {
            int r = i >> 4, c8 = i & 15;
            int gr = row0 + r;
            u8v raw = {0, 0, 0, 0, 0, 0, 0, 0};
            if (gr < n) raw = *(const u8v*)(X + (size_t)gr * 128 + c8 * 8);
            ushort o[8];
            #pragma unroll
            for (int j = 0; j < 8; ++j) {
                float f = fmaf(bf2f(raw[j]), abuf[c8 * 8 + j], bbuf[c8 * 8 + j]);
                if (relu) f = fmaxf(f, 0.f);
                o[j] = f2bf(f);
            }
            int off = (r * 256 + c8 * 16) ^ ((r & 7) << 4);
            ushort4* dst = (ushort4*)((char*)xb + off);
            dst[0] = make_ushort4(o[0], o[1], o[2], o[3]);
            dst[1] = make_ushort4(o[4], o[5], o[6], o[7]);
        }
    } else {
        const float* X = (const float*)Xv;
        for (int i = tid; i < 64 * 32; i += 256) {
            int r = i >> 5, c4 = i & 31;
            int gr = row0 + r;
            float4 v = make_float4(0.f, 0.f, 0.f, 0.f);
            if (gr < n) v = ((const float4*)X)[(size_t)gr * 32 + c4];
            float4 a4 = *(const float4*)&abuf[c4 * 4];
            float4 b4 = *(const float4*)&bbuf[c4 * 4];
            v.x = fmaf(v.x, a4.x, b4.x);
            v.y = fmaf(v.y, a4.y, b4.y);
            v.z = fmaf(v.z, a4.z, b4.z);
            v.w = fmaf(v.w, a4.w, b4.w);
            if (relu) {
                v.x = fmaxf(v.x, 0.f); v.y = fmaxf(v.y, 0.f);
                v.z = fmaxf(v.z, 0.f); v.w = fmaxf(v.w, 0.f);
            }
            ushort4 pk = make_ushort4(f2bf(v.x), f2bf(v.y), f2bf(v.z), f2bf(v.w));
            int off = (r * 256 + c4 * 8) ^ ((r & 7) << 4);
            *(ushort4*)((char*)xb + off) = pk;
        }
    }
    __syncthreads();

    const int wv = tid >> 6;
    const int l  = tid & 63;
    const int arow = wv * 16 + (l & 15);

    s8v afr[4];
    #pragma unroll
    for (int ks = 0; ks < 4; ++ks) {
        int off = (arow * 256 + ks * 64 + ((l >> 4) << 4)) ^ ((arow & 7) << 4);
        afr[ks] = *(const s8v*)((const char*)xb + off);
    }

    const s8v* wf = (const s8v*)Wswz;
    f4v acc[8];
    #pragma unroll
    for (int ct = 0; ct < 8; ++ct) {
        f4v c = {0.f, 0.f, 0.f, 0.f};
        #pragma unroll
        for (int ks = 0; ks < 4; ++ks) {
            s8v bb = wf[(ct * 4 + ks) * 64 + l];
            c = __builtin_amdgcn_mfma_f32_16x16x32_bf16(afr[ks], bb, c, 0, 0, 0);
        }
        acc[ct] = c;
    }

    const int rbase = row0 + wv * 16 + ((l >> 4) << 2);
    const int cidx  = l & 15;
    #pragma unroll
    for (int r = 0; r < 4; ++r) {
        int gr = rbase + r;
        if (gr < n) {
            #pragma unroll
            for (int ct = 0; ct < 8; ++ct)
                H[(size_t)gr * 128 + ct * 16 + cidx] = f2bf(acc[ct][r]);
        }
    }
}

// ---- aggregation: one wave per node, 4 edges/instr, bf16 AGG out ----------
template<int NP>
__device__ inline void quad_batch(const ushort* __restrict__ H,
                                  const int2* __restrict__ ep,
                                  int i, int q, int sl, float* __restrict__ a) {
    int2 p[NP]; uint4 v[NP];
    #pragma unroll
    for (int k = 0; k < NP; ++k) p[k] = ep[i + 4 * k + q];
    #pragma unroll
    for (int k = 0; k < NP; ++k)
        v[k] = ((const uint4*)(H + (size_t)p[k].x * 128))[sl];
    #pragma unroll
    for (int k = 0; k < NP; ++k) {
        float w = __int_as_float(p[k].y);
        float2 f0 = bf2f2(v[k].x), f1 = bf2f2(v[k].y);
        float2 f2 = bf2f2(v[k].z), f3 = bf2f2(v[k].w);
        a[0] = fmaf(w, f0.x, a[0]); a[1] = fmaf(w, f0.y, a[1]);
        a[2] = fmaf(w, f1.x, a[2]); a[3] = fmaf(w, f1.y, a[3]);
        a[4] = fmaf(w, f2.x, a[4]); a[5] = fmaf(w, f2.y, a[5]);
        a[6] = fmaf(w, f3.x, a[6]); a[7] = fmaf(w, f3.y, a[7]);
    }
}

__global__ __launch_bounds__(256) void k_aggregate(const ushort* __restrict__ H,
                                                   const int* __restrict__ rs,
                                                   const int2* __restrict__ ep,
                                                   const float* __restrict__ dinv,
                                                   ushort* __restrict__ AGG,
                                                   float* __restrict__ part, int n) {
    __shared__ float red[4][128];
    __shared__ float redq[4][128];
    const int wv   = threadIdx.x >> 6;
    const int lane = threadIdx.x & 63;
    const int q    = lane >> 4;      // quarter 0..3
    const int sl   = lane & 15;      // 16 lanes x 16B per row
    const int node = blockIdx.x * 4 + wv;
    float a[8] = {0.f, 0.f, 0.f, 0.f, 0.f, 0.f, 0.f, 0.f};

    if (node < n) {
        if (q == 0) {   // self term on quarter 0 only
            float sn = dinv[node]; sn *= sn;
            uint4 sv = ((const uint4*)(H + (size_t)node * 128))[sl];
            float2 f0 = bf2f2(sv.x), f1 = bf2f2(sv.y);
            float2 f2 = bf2f2(sv.z), f3 = bf2f2(sv.w);
            a[0] = sn * f0.x; a[1] = sn * f0.y;
            a[2] = sn * f1.x; a[3] = sn * f1.y;
            a[4] = sn * f2.x; a[5] = sn * f2.y;
            a[6] = sn * f3.x; a[7] = sn * f3.y;
        }
        int i  = rs[node];
        int i1 = rs[node + 1];
        for (; i + 16 <= i1; i += 16) quad_batch<4>(H, ep, i, q, sl, a);
        if (i + 8 <= i1) { quad_batch<2>(H, ep, i, q, sl, a); i += 8; }
        if (i + 4 <= i1) { quad_batch<1>(H, ep, i, q, sl, a); i += 4; }
        if (i < i1) {   // 1..3 leftover: inactive quarters use w=0
            int idx = min(i + q, i1 - 1);
            int2 p = ep[idx];
            float w = (i + q < i1) ? __int_as_float(p.y) : 0.f;
            uint4 v = ((const uint4*)(H + (size_t)p.x * 128))[sl];
            float2 f0 = bf2f2(v.x), f1 = bf2f2(v.y);
            float2 f2 = bf2f2(v.z), f3 = bf2f2(v.w);
            a[0] = fmaf(w, f0.x, a[0]); a[1] = fmaf(w, f0.y, a[1]);
            a[2] = fmaf(w, f1.x, a[2]); a[3] = fmaf(w, f1.y, a[3]);
            a[4] = fmaf(w, f2.x, a[4]); a[5] = fmaf(w, f2.y, a[5]);
            a[6] = fmaf(w, f3.x, a[6]); a[7] = fmaf(w, f3.y, a[7]);
        }
        #pragma unroll
        for (int j = 0; j < 8; ++j) {
            a[j] += __shfl_xor(a[j], 16);
            a[j] += __shfl_xor(a[j], 32);
        }
        if (q == 0) {
            u8v o;
            #pragma unroll
            for (int j = 0; j < 8; ++j) o[j] = f2bf(a[j]);
            *(u8v*)(AGG + (size_t)node * 128 + sl * 8) = o;
        }
    }

    // fused BN stats (fp32, pre-rounding): quarter-0 lanes own cols 8sl..8sl+7
    if (q == 0) {
        *(float4*)&red[wv][8 * sl]      = make_float4(a[0], a[1], a[2], a[3]);
        *(float4*)&red[wv][8 * sl + 4]  = make_float4(a[4], a[5], a[6], a[7]);
        *(float4*)&redq[wv][8 * sl]     = make_float4(a[0] * a[0], a[1] * a[1],
                                                      a[2] * a[2], a[3] * a[3]);
        *(float4*)&redq[wv][8 * sl + 4] = make_float4(a[4] * a[4], a[5] * a[5],
                                                      a[6] * a[6], a[7] * a[7]);
    }
    __syncthreads();
    const int t = threadIdx.x;
    if (t < 128)
        part[(size_t)blockIdx.x * 256 + t] =
            red[0][t] + red[1][t] + red[2][t] + red[3][t];
    else {
        int c = t - 128;
        part[(size_t)blockIdx.x * 256 + t] =
            redq[0][c] + redq[1][c] + redq[2][c] + redq[3][c];
    }
}

// ---- final projection: OUT = relu(a*X+b) @ Wf + bf (bf16 X, 128 -> 40) ----
__global__ __launch_bounds__(256) void k_gemm_out(const ushort* __restrict__ X,
                                                  const float* __restrict__ Wf,
                                                  const float* __restrict__ bfv,
                                                  const float* __restrict__ part2,
                                                  const float* __restrict__ g,
                                                  const float* __restrict__ be,
                                                  float invn,
                                                  float* __restrict__ OUT, int n) {
    __shared__ float xl[32 * 132];
    __shared__ float wt[40 * 132];
    __shared__ float tmp[256];
    __shared__ float abuf[128], bbuf[128];
    const int tid = threadIdx.x;

    bn_inblock(part2, g, be, invn, tmp, abuf, bbuf);

    for (int i = tid; i < 128 * 40; i += 256) {
        int c = i / 40;
        int j = i - c * 40;
        wt[j * 132 + c] = Wf[i];
    }
    const int row0 = blockIdx.x * 32;
    for (int i = tid; i < 32 * 16; i += 256) {
        int r = i >> 4, c8 = i & 15;
        int gr = row0 + r;
        u8v raw = {0, 0, 0, 0, 0, 0, 0, 0};
        if (gr < n) raw = *(const u8v*)(X + (size_t)gr * 128 + c8 * 8);
        float o[8];
        #pragma unroll
        for (int j = 0; j < 8; ++j)
            o[j] = fmaxf(fmaf(bf2f(raw[j]), abuf[c8 * 8 + j],
                              bbuf[c8 * 8 + j]), 0.f);
        *(float4*)&xl[r * 132 + c8 * 8]     = make_float4(o[0], o[1], o[2], o[3]);
        *(float4*)&xl[r * 132 + c8 * 8 + 4] = make_float4(o[4], o[5], o[6], o[7]);
    }
    __syncthreads();

    const int rg = tid >> 3;
    const int cg = tid & 7;
    const int j0 = cg * 5;
    float acc[5] = {0.f, 0.f, 0.f, 0.f, 0.f};
    for (int c = 0; c < 128; c += 4) {
        float4 xv = *(const float4*)&xl[rg * 132 + c];
        #pragma unroll
        for (int j = 0; j < 5; ++j) {
            float4 wv = *(const float4*)&wt[(j0 + j) * 132 + c];
            acc[j] = fmaf(xv.x, wv.x, acc[j]);
            acc[j] = fmaf(xv.y, wv.y, acc[j]);
            acc[j] = fmaf(xv.z, wv.z, acc[j]);
            acc[j] = fmaf(xv.w, wv.w, acc[j]);
        }
    }
    int gr = row0 + rg;
    if (gr < n) {
        #pragma unroll
        for (int j = 0; j < 5; ++j)
            OUT[(size_t)gr * 40 + j0 + j] = acc[j] + bfv[j0 + j];
    }
}

// ---------------------------------------------------------------------------
extern "C" void kernel_launch(void* const* d_in, const int* in_sizes, int n_in,
                              void* d_out, int out_size, void* d_ws, size_t ws_size,
                              hipStream_t stream) {
    const float* X0      = (const float*)d_in[0];
    const int*   edgesrc = (const int*)d_in[1];
    const int*   edgedst = (const int*)d_in[2];
    const float* bn0g = (const float*)d_in[3];
    const float* bn0b = (const float*)d_in[4];
    const float* W1   = (const float*)d_in[5];
    const float* bn1g = (const float*)d_in[7];
    const float* bn1b = (const float*)d_in[8];
    const float* W2   = (const float*)d_in[9];
    const float* bn2g = (const float*)d_in[11];
    const float* bn2b = (const float*)d_in[12];
    const float* Wf   = (const float*)d_in[13];
    const float* bfv  = (const float*)d_in[14];

    const int n = in_sizes[0] / 128;
    const int e = in_sizes[1];
    float* OUT = (float*)d_out;

    const int aggBlocks = (n + 3) / 4;               // one wave per node

    // workspace layout
    ushort* H    = (ushort*)d_ws;                     // n*128 bf16
    ushort* AGGb = H + (size_t)n * 128;               // n*128 bf16
    float*  dinv = (float*)(AGGb + (size_t)n * 128);  // n
    int2*   ep   = (int2*)(dinv + n);                 // e
    ushort* Wswz = (ushort*)(ep + e);                 // 2 * 16384 bf16
    int*    cnt  = (int*)(Wswz + 2 * 16384);          // n
    int*    rs   = cnt + n;                           // n+1
    int*    rank = rs + n + 1;                        // e
    int*    bsum = rank + e;                          // 64
    float*  part = (float*)(bsum + 64);               // aggBlocks*256 (12.8MB)
    float* part2 = part + (size_t)aggBlocks * 256;    // 64*256

    const float invn = 1.f / (float)n;
    const int nb = (n + 1023) / 1024;
    const int fillBlocks = (e + 255) / 256;

    // fused prologue: colstats(X0) + W swizzle + cnt zero
    k_prolog<<<CS_BLOCKS + 16 + 64, 256, 0, stream>>>(X0, n, part, W1, W2,
                                                      Wswz, cnt);

    // CSR build
    k_count<<<(e + 255) / 256, 256, 0, stream>>>(edgedst, e, cnt, rank);
    k_scanA<<<nb, 1024, 0, stream>>>(cnt, n, rs, bsum);
    k_scanC<<<(n + 255) / 256, 256, 0, stream>>>(rs, bsum, cnt, dinv, n, e);
    // fill + layer-1 redA (independent roles in one dispatch)
    k_fill<<<fillBlocks + 64, 256, 0, stream>>>(edgesrc, edgedst, e, rs, rank,
                                                dinv, ep, part, part2,
                                                fillBlocks);

    const int gemmBlocks = (n + 63) / 64;

    // layer 1
    k_gemm_mfma<0><<<gemmBlocks, 256, 0, stream>>>(X0, Wswz, part2, bn0g, bn0b,
                                                   invn, 0, H, n);
    k_aggregate<<<aggBlocks, 256, 0, stream>>>(H, rs, ep, dinv, AGGb, part, n);

    // layer 2 (stats of AGG came fused from aggregate)
    k_redA<<<64, 256, 0, stream>>>(part, part2, aggBlocks);
    k_gemm_mfma<1><<<gemmBlocks, 256, 0, stream>>>(AGGb, Wswz + 16384, part2,
                                                   bn1g, bn1b, invn, 1, H, n);
    k_aggregate<<<aggBlocks, 256, 0, stream>>>(H, rs, ep, dinv, AGGb, part, n);

    // head
    k_redA<<<64, 256, 0, stream>>>(part, part2, aggBlocks);
    k_gemm_out<<<(n + 31) / 32, 256, 0, stream>>>(AGGb, Wf, bfv, part2, bn2g,
                                                  bn2b, invn, OUT, n);
}

// Round 12
// 218.789 us; speedup vs baseline: 1.1738x; 1.0540x over previous
//
#include <hip/hip_runtime.h>
#include <cstdint>
#include <cstddef>

// ---------------------------------------------------------------------------
// GCN: out = relu(BN2(A' relu(BN1(A' BN0(X) W1)) W2)) Wf + bf
// A' = D^-1/2 (A+I) D^-1/2 via per-call CSR (sorted by dst).
// Conv biases b1,b2 cancel inside the following BatchNorm and are skipped.
// BN affine folded into each GEMM block (from 64-row part2). GEMMs bf16 MFMA
// 16x16x32. H AND AGG stored bf16; BN stats fp32 (from registers pre-round).
// Aggregate: one wave per node, 4 edges/instr (quarter-waves, dwordx4),
// batches 16/12/8/4 for MLP depth; fused BN stats.
// r12: role-fused dispatches — {scanC+redA1} and {fill+gemm1} — 12->10 graph
// nodes (linear dep chain; ~4-5us gap per node measured r7/r8).
// No hipMemsetAsync (r7), no float atomics / no threadfence (r3).
// ---------------------------------------------------------------------------

#define CS_BLOCKS 512

typedef short  s8v __attribute__((ext_vector_type(8)));
typedef ushort u8v __attribute__((ext_vector_type(8)));
typedef float  f4v __attribute__((ext_vector_type(4)));

__device__ inline ushort f2bf(float f) {            // RNE float->bf16
    uint u = __float_as_uint(f);
    return (ushort)((u + 0x7fffu + ((u >> 16) & 1u)) >> 16);
}
__device__ inline float bf2f(ushort u) {
    return __uint_as_float((uint)u << 16);
}
__device__ inline float2 bf2f2(uint u) {            // packed 2xbf16 -> 2xf32
    float2 r;
    r.x = __uint_as_float(u << 16);
    r.y = __uint_as_float(u & 0xffff0000u);
    return r;
}

// ---- fused prologue: colstats(X0) + W frag-swizzle + cnt zero -------------
__global__ __launch_bounds__(256) void k_prolog(const float* __restrict__ X,
                                                int n, float* __restrict__ part,
                                                const float* __restrict__ W1,
                                                const float* __restrict__ W2,
                                                ushort* __restrict__ Wswz,
                                                int* __restrict__ cnt) {
    const int bid = blockIdx.x;
    if (bid < CS_BLOCKS) {
        __shared__ float ls[8 * 128];
        __shared__ float lq[8 * 128];
        const int c4    = threadIdx.x & 31;
        const int rslot = threadIdx.x >> 5;
        float4 s4 = make_float4(0.f, 0.f, 0.f, 0.f);
        float4 q4 = make_float4(0.f, 0.f, 0.f, 0.f);
        const float4* X4 = (const float4*)X;
        for (int r = bid * 8 + rslot; r < n; r += CS_BLOCKS * 8) {
            float4 v = X4[(size_t)r * 32 + c4];
            s4.x += v.x; s4.y += v.y; s4.z += v.z; s4.w += v.w;
            q4.x = fmaf(v.x, v.x, q4.x); q4.y = fmaf(v.y, v.y, q4.y);
            q4.z = fmaf(v.z, v.z, q4.z); q4.w = fmaf(v.w, v.w, q4.w);
        }
        *(float4*)&ls[rslot * 128 + c4 * 4] = s4;
        *(float4*)&lq[rslot * 128 + c4 * 4] = q4;
        __syncthreads();
        float t = 0.f;
        if (threadIdx.x < 128) {
            int c = threadIdx.x;
            #pragma unroll
            for (int k = 0; k < 8; ++k) t += ls[k * 128 + c];
        } else {
            int c = threadIdx.x - 128;
            #pragma unroll
            for (int k = 0; k < 8; ++k) t += lq[k * 128 + c];
        }
        part[bid * 256 + threadIdx.x] = t;
    } else if (bid < CS_BLOCKS + 16) {
        const int wb = bid - CS_BLOCKS;
        const float* W = (wb < 8) ? W1 : W2;
        ushort* out = Wswz + (wb < 8 ? 0 : 16384);
        int t  = (wb & 7) * 256 + threadIdx.x;    // 0..2047
        int l  = t & 63;
        int fi = t >> 6;
        int ks = fi & 3, ct = fi >> 2;
        int c  = ct * 16 + (l & 15);
        int k0 = ks * 32 + ((l >> 4) << 3);
        ushort o[8];
        #pragma unroll
        for (int j = 0; j < 8; ++j)
            o[j] = f2bf(W[(size_t)(k0 + j) * 128 + c]);
        ushort4* dst = (ushort4*)(out + (size_t)t * 8);
        dst[0] = make_ushort4(o[0], o[1], o[2], o[3]);
        dst[1] = make_ushort4(o[4], o[5], o[6], o[7]);
    } else {
        const int zb = bid - CS_BLOCKS - 16;      // 0..63
        const int nv = n >> 2;
        int4* c4p = (int4*)cnt;
        const int4 z = make_int4(0, 0, 0, 0);
        for (int i = zb * 256 + threadIdx.x; i < nv; i += 64 * 256)
            c4p[i] = z;
        int i = (nv << 2) + zb * 256 + threadIdx.x;
        if (i < n) cnt[i] = 0;
    }
}

// ---- collapse nrows partial rows -> 64 rows (role-shared helper) ----------
__device__ inline void redA_body(const float* __restrict__ part,
                                 float* __restrict__ part2,
                                 int nrows, int b) {
    const int c = threadIdx.x;
    const int per = (nrows + 63) >> 6;
    const int r0 = b * per;
    const int r1 = min(r0 + per, nrows);
    float t0 = 0.f, t1 = 0.f;
    int r = r0;
    for (; r + 2 <= r1; r += 2) {
        t0 += part[(size_t)r * 256 + c];
        t1 += part[(size_t)(r + 1) * 256 + c];
    }
    if (r < r1) t0 += part[(size_t)r * 256 + c];
    part2[b * 256 + c] = t0 + t1;
}

__global__ __launch_bounds__(256) void k_redA(const float* __restrict__ part,
                                              float* __restrict__ part2,
                                              int nrows) {
    redA_body(part, part2, nrows, blockIdx.x);
}

// ---- in-block BN finalize from part2 (64 rows x 256) ----------------------
__device__ inline void bn_inblock(const float* __restrict__ part2,
                                  const float* __restrict__ g,
                                  const float* __restrict__ be,
                                  float invn, float* __restrict__ tmp,
                                  float* __restrict__ abuf,
                                  float* __restrict__ bbuf) {
    const int tid = threadIdx.x;
    float t = 0.f;
    #pragma unroll 8
    for (int r = 0; r < 64; ++r) t += part2[r * 256 + tid];
    tmp[tid] = t;
    __syncthreads();
    if (tid < 128) {
        float mu  = tmp[tid] * invn;
        float var = tmp[tid + 128] * invn - mu * mu;
        float av  = g[tid] * rsqrtf(var + 1e-5f);
        abuf[tid] = av;
        bbuf[tid] = be[tid] - mu * av;
    }
    __syncthreads();
}

// ---- CSR build ------------------------------------------------------------
__global__ __launch_bounds__(256) void k_count(const int* __restrict__ dst, int e,
                                               int* __restrict__ cnt,
                                               int* __restrict__ rank) {
    int i = blockIdx.x * 256 + threadIdx.x;
    if (i < e) rank[i] = atomicAdd(&cnt[dst[i]], 1);
}

__global__ __launch_bounds__(1024) void k_scanA(const int* __restrict__ cnt, int n,
                                                int* __restrict__ rs, int* __restrict__ bsum) {
    __shared__ int tmp[1024];
    int t = threadIdx.x;
    int i = blockIdx.x * 1024 + t;
    int v = (i < n) ? cnt[i] : 0;
    tmp[t] = v;
    __syncthreads();
    for (int off = 1; off < 1024; off <<= 1) {
        int x = (t >= off) ? tmp[t - off] : 0;
        __syncthreads();
        tmp[t] += x;
        __syncthreads();
    }
    if (i < n) rs[i] = tmp[t] - v;
    if (t == 1023) bsum[blockIdx.x] = tmp[t];
}

// scanC + layer-1 redA fused (independent roles)
__global__ __launch_bounds__(256) void k_scanC(int* __restrict__ rs,
                                               const int* __restrict__ bsum,
                                               const int* __restrict__ cnt,
                                               float* __restrict__ dinv,
                                               int n, int e,
                                               const float* __restrict__ part,
                                               float* __restrict__ part2,
                                               int scanBlocks) {
    const int bid = blockIdx.x;
    if (bid >= scanBlocks) {
        redA_body(part, part2, CS_BLOCKS, bid - scanBlocks);
        return;
    }
    __shared__ int base;
    int chunk = (int)(bid >> 2);
    if (threadIdx.x == 0) {
        int s = 0;
        for (int c = 0; c < chunk; ++c) s += bsum[c];
        base = s;
    }
    __syncthreads();
    int i = bid * 256 + threadIdx.x;
    if (i < n) {
        rs[i] += base;
        dinv[i] = rsqrtf((float)(cnt[i] + 1));
    }
    if (bid == 0 && threadIdx.x == 0) rs[n] = e;
}

// ---- MFMA GEMM body: H_bf16[row0..row0+63][128] = bf16( f(X) @ W ) --------
template<int BF16IN>
__device__ inline void gemm_body(const void* __restrict__ Xv,
                                 const ushort* __restrict__ Wswz,
                                 const float* __restrict__ part2,
                                 const float* __restrict__ g,
                                 const float* __restrict__ be,
                                 float invn, int relu,
                                 ushort* __restrict__ H, int n, int row0) {
    __shared__ ushort xb[64 * 128];   // 16 KB, swizzled: byte ^= (row&7)<<4
    __shared__ float tmp[256];
    __shared__ float abuf[128], bbuf[128];
    const int tid = threadIdx.x;

    bn_inblock(part2, g, be, invn, tmp, abuf, bbuf);

    if (BF16IN) {
        const ushort* X = (const ushort*)Xv;
        for (int i = tid; i < 64 * 16; i += 256) {
            int r = i >> 4, c8 = i & 15;
            int gr = row0 + r;
            u8v raw = {0, 0, 0, 0, 0, 0, 0, 0};
            if (gr < n) raw = *(const u8v*)(X + (size_t)gr * 128 + c8 * 8);
            ushort o[8];
            #pragma unroll
            for (int j = 0; j < 8; ++j) {
                float f = fmaf(bf2f(raw[j]), abuf[c8 * 8 + j], bbuf[c8 * 8 + j]);
                if (relu) f = fmaxf(f, 0.f);
                o[j] = f2bf(f);
            }
            int off = (r * 256 + c8 * 16) ^ ((r & 7) << 4);
            ushort4* dst = (ushort4*)((char*)xb + off);
            dst[0] = make_ushort4(o[0], o[1], o[2], o[3]);
            dst[1] = make_ushort4(o[4], o[5], o[6], o[7]);
        }
    } else {
        const float* X = (const float*)Xv;
        for (int i = tid; i < 64 * 32; i += 256) {
            int r = i >> 5, c4 = i & 31;
            int gr = row0 + r;
            float4 v = make_float4(0.f, 0.f, 0.f, 0.f);
            if (gr < n) v = ((const float4*)X)[(size_t)gr * 32 + c4];
            float4 a4 = *(const float4*)&abuf[c4 * 4];
            float4 b4 = *(const float4*)&bbuf[c4 * 4];
            v.x = fmaf(v.x, a4.x, b4.x);
            v.y = fmaf(v.y, a4.y, b4.y);
            v.z = fmaf(v.z, a4.z, b4.z);
            v.w = fmaf(v.w, a4.w, b4.w);
            if (relu) {
                v.x = fmaxf(v.x, 0.f); v.y = fmaxf(v.y, 0.f);
                v.z = fmaxf(v.z, 0.f); v.w = fmaxf(v.w, 0.f);
            }
            ushort4 pk = make_ushort4(f2bf(v.x), f2bf(v.y), f2bf(v.z), f2bf(v.w));
            int off = (r * 256 + c4 * 8) ^ ((r & 7) << 4);
            *(ushort4*)((char*)xb + off) = pk;
        }
    }
    __syncthreads();

    const int wv = tid >> 6;
    const int l  = tid & 63;
    const int arow = wv * 16 + (l & 15);

    s8v afr[4];
    #pragma unroll
    for (int ks = 0; ks < 4; ++ks) {
        int off = (arow * 256 + ks * 64 + ((l >> 4) << 4)) ^ ((arow & 7) << 4);
        afr[ks] = *(const s8v*)((const char*)xb + off);
    }

    const s8v* wf = (const s8v*)Wswz;
    f4v acc[8];
    #pragma unroll
    for (int ct = 0; ct < 8; ++ct) {
        f4v c = {0.f, 0.f, 0.f, 0.f};
        #pragma unroll
        for (int ks = 0; ks < 4; ++ks) {
            s8v bb = wf[(ct * 4 + ks) * 64 + l];
            c = __builtin_amdgcn_mfma_f32_16x16x32_bf16(afr[ks], bb, c, 0, 0, 0);
        }
        acc[ct] = c;
    }

    const int rbase = row0 + wv * 16 + ((l >> 4) << 2);
    const int cidx  = l & 15;
    #pragma unroll
    for (int r = 0; r < 4; ++r) {
        int gr = rbase + r;
        if (gr < n) {
            #pragma unroll
            for (int ct = 0; ct < 8; ++ct)
                H[(size_t)gr * 128 + ct * 16 + cidx] = f2bf(acc[ct][r]);
        }
    }
}

// standalone GEMM (layer 2, bf16 input)
__global__ __launch_bounds__(256) void k_gemm_mfma(const ushort* __restrict__ X,
                                                   const ushort* __restrict__ Wswz,
                                                   const float* __restrict__ part2,
                                                   const float* __restrict__ g,
                                                   const float* __restrict__ be,
                                                   float invn, int relu,
                                                   ushort* __restrict__ H, int n) {
    gemm_body<1>(X, Wswz, part2, g, be, invn, relu, H, n, blockIdx.x * 64);
}

// fused: layer-1 GEMM (fp32 input) + CSR fill (independent roles)
__global__ __launch_bounds__(256) void k_gemm_fill(const float* __restrict__ X,
                                                   const ushort* __restrict__ Wswz,
                                                   const float* __restrict__ part2,
                                                   const float* __restrict__ g,
                                                   const float* __restrict__ be,
                                                   float invn,
                                                   ushort* __restrict__ H, int n,
                                                   int gemmBlocks,
                                                   const int* __restrict__ src,
                                                   const int* __restrict__ dst,
                                                   int e,
                                                   const int* __restrict__ rs,
                                                   const int* __restrict__ rank,
                                                   const float* __restrict__ dinv,
                                                   int2* __restrict__ ep) {
    const int bid = blockIdx.x;
    if (bid < gemmBlocks) {
        gemm_body<0>(X, Wswz, part2, g, be, invn, 0, H, n, bid * 64);
    } else {
        int i = (bid - gemmBlocks) * 256 + threadIdx.x;
        if (i < e) {
            int d = dst[i], s = src[i];
            int p = rs[d] + rank[i];
            float nm = dinv[s] * dinv[d];
            ep[p] = make_int2(s, __float_as_int(nm));
        }
    }
}

// ---- aggregation: one wave per node, 4 edges/instr, bf16 AGG out ----------
template<int NP>
__device__ inline void quad_batch(const ushort* __restrict__ H,
                                  const int2* __restrict__ ep,
                                  int i, int q, int sl, float* __restrict__ a) {
    int2 p[NP]; uint4 v[NP];
    #pragma unroll
    for (int k = 0; k < NP; ++k) p[k] = ep[i + 4 * k + q];
    #pragma unroll
    for (int k = 0; k < NP; ++k)
        v[k] = ((const uint4*)(H + (size_t)p[k].x * 128))[sl];
    #pragma unroll
    for (int k = 0; k < NP; ++k) {
        float w = __int_as_float(p[k].y);
        float2 f0 = bf2f2(v[k].x), f1 = bf2f2(v[k].y);
        float2 f2 = bf2f2(v[k].z), f3 = bf2f2(v[k].w);
        a[0] = fmaf(w, f0.x, a[0]); a[1] = fmaf(w, f0.y, a[1]);
        a[2] = fmaf(w, f1.x, a[2]); a[3] = fmaf(w, f1.y, a[3]);
        a[4] = fmaf(w, f2.x, a[4]); a[5] = fmaf(w, f2.y, a[5]);
        a[6] = fmaf(w, f3.x, a[6]); a[7] = fmaf(w, f3.y, a[7]);
    }
}

__global__ __launch_bounds__(256) void k_aggregate(const ushort* __restrict__ H,
                                                   const int* __restrict__ rs,
                                                   const int2* __restrict__ ep,
                                                   const float* __restrict__ dinv,
                                                   ushort* __restrict__ AGG,
                                                   float* __restrict__ part, int n) {
    __shared__ float red[4][128];
    __shared__ float redq[4][128];
    const int wv   = threadIdx.x >> 6;
    const int lane = threadIdx.x & 63;
    const int q    = lane >> 4;      // quarter 0..3
    const int sl   = lane & 15;      // 16 lanes x 16B per row
    const int node = blockIdx.x * 4 + wv;
    float a[8] = {0.f, 0.f, 0.f, 0.f, 0.f, 0.f, 0.f, 0.f};

    if (node < n) {
        if (q == 0) {   // self term on quarter 0 only
            float sn = dinv[node]; sn *= sn;
            uint4 sv = ((const uint4*)(H + (size_t)node * 128))[sl];
            float2 f0 = bf2f2(sv.x), f1 = bf2f2(sv.y);
            float2 f2 = bf2f2(sv.z), f3 = bf2f2(sv.w);
            a[0] = sn * f0.x; a[1] = sn * f0.y;
            a[2] = sn * f1.x; a[3] = sn * f1.y;
            a[4] = sn * f2.x; a[5] = sn * f2.y;
            a[6] = sn * f3.x; a[7] = sn * f3.y;
        }
        int i  = rs[node];
        int i1 = rs[node + 1];
        for (; i + 16 <= i1; i += 16) quad_batch<4>(H, ep, i, q, sl, a);
        if (i + 12 <= i1) { quad_batch<3>(H, ep, i, q, sl, a); i += 12; }
        if (i + 8  <= i1) { quad_batch<2>(H, ep, i, q, sl, a); i += 8; }
        if (i + 4  <= i1) { quad_batch<1>(H, ep, i, q, sl, a); i += 4; }
        if (i < i1) {   // 1..3 leftover: inactive quarters use w=0
            int idx = min(i + q, i1 - 1);
            int2 p = ep[idx];
            float w = (i + q < i1) ? __int_as_float(p.y) : 0.f;
            uint4 v = ((const uint4*)(H + (size_t)p.x * 128))[sl];
            float2 f0 = bf2f2(v.x), f1 = bf2f2(v.y);
            float2 f2 = bf2f2(v.z), f3 = bf2f2(v.w);
            a[0] = fmaf(w, f0.x, a[0]); a[1] = fmaf(w, f0.y, a[1]);
            a[2] = fmaf(w, f1.x, a[2]); a[3] = fmaf(w, f1.y, a[3]);
            a[4] = fmaf(w, f2.x, a[4]); a[5] = fmaf(w, f2.y, a[5]);
            a[6] = fmaf(w, f3.x, a[6]); a[7] = fmaf(w, f3.y, a[7]);
        }
        #pragma unroll
        for (int j = 0; j < 8; ++j) {
            a[j] += __shfl_xor(a[j], 16);
            a[j] += __shfl_xor(a[j], 32);
        }
        if (q == 0) {
            u8v o;
            #pragma unroll
            for (int j = 0; j < 8; ++j) o[j] = f2bf(a[j]);
            *(u8v*)(AGG + (size_t)node * 128 + sl * 8) = o;
        }
    }

    // fused BN stats (fp32, pre-rounding): quarter-0 lanes own cols 8sl..8sl+7
    if (q == 0) {
        *(float4*)&red[wv][8 * sl]      = make_float4(a[0], a[1], a[2], a[3]);
        *(float4*)&red[wv][8 * sl + 4]  = make_float4(a[4], a[5], a[6], a[7]);
        *(float4*)&redq[wv][8 * sl]     = make_float4(a[0] * a[0], a[1] * a[1],
                                                      a[2] * a[2], a[3] * a[3]);
        *(float4*)&redq[wv][8 * sl + 4] = make_float4(a[4] * a[4], a[5] * a[5],
                                                      a[6] * a[6], a[7] * a[7]);
    }
    __syncthreads();
    const int t = threadIdx.x;
    if (t < 128)
        part[(size_t)blockIdx.x * 256 + t] =
            red[0][t] + red[1][t] + red[2][t] + red[3][t];
    else {
        int c = t - 128;
        part[(size_t)blockIdx.x * 256 + t] =
            redq[0][c] + redq[1][c] + redq[2][c] + redq[3][c];
    }
}

// ---- final projection: OUT = relu(a*X+b) @ Wf + bf (bf16 X, 128 -> 40) ----
__global__ __launch_bounds__(256) void k_gemm_out(const ushort* __restrict__ X,
                                                  const float* __restrict__ Wf,
                                                  const float* __restrict__ bfv,
                                                  const float* __restrict__ part2,
                                                  const float* __restrict__ g,
                                                  const float* __restrict__ be,
                                                  float invn,
                                                  float* __restrict__ OUT, int n) {
    __shared__ float xl[32 * 132];
    __shared__ float wt[40 * 132];
    __shared__ float tmp[256];
    __shared__ float abuf[128], bbuf[128];
    const int tid = threadIdx.x;

    bn_inblock(part2, g, be, invn, tmp, abuf, bbuf);

    for (int i = tid; i < 128 * 40; i += 256) {
        int c = i / 40;
        int j = i - c * 40;
        wt[j * 132 + c] = Wf[i];
    }
    const int row0 = blockIdx.x * 32;
    for (int i = tid; i < 32 * 16; i += 256) {
        int r = i >> 4, c8 = i & 15;
        int gr = row0 + r;
        u8v raw = {0, 0, 0, 0, 0, 0, 0, 0};
        if (gr < n) raw = *(const u8v*)(X + (size_t)gr * 128 + c8 * 8);
        float o[8];
        #pragma unroll
        for (int j = 0; j < 8; ++j)
            o[j] = fmaxf(fmaf(bf2f(raw[j]), abuf[c8 * 8 + j],
                              bbuf[c8 * 8 + j]), 0.f);
        *(float4*)&xl[r * 132 + c8 * 8]     = make_float4(o[0], o[1], o[2], o[3]);
        *(float4*)&xl[r * 132 + c8 * 8 + 4] = make_float4(o[4], o[5], o[6], o[7]);
    }
    __syncthreads();

    const int rg = tid >> 3;
    const int cg = tid & 7;
    const int j0 = cg * 5;
    float acc[5] = {0.f, 0.f, 0.f, 0.f, 0.f};
    for (int c = 0; c < 128; c += 4) {
        float4 xv = *(const float4*)&xl[rg * 132 + c];
        #pragma unroll
        for (int j = 0; j < 5; ++j) {
            float4 wv = *(const float4*)&wt[(j0 + j) * 132 + c];
            acc[j] = fmaf(xv.x, wv.x, acc[j]);
            acc[j] = fmaf(xv.y, wv.y, acc[j]);
            acc[j] = fmaf(xv.z, wv.z, acc[j]);
            acc[j] = fmaf(xv.w, wv.w, acc[j]);
        }
    }
    int gr = row0 + rg;
    if (gr < n) {
        #pragma unroll
        for (int j = 0; j < 5; ++j)
            OUT[(size_t)gr * 40 + j0 + j] = acc[j] + bfv[j0 + j];
    }
}

// ---------------------------------------------------------------------------
extern "C" void kernel_launch(void* const* d_in, const int* in_sizes, int n_in,
                              void* d_out, int out_size, void* d_ws, size_t ws_size,
                              hipStream_t stream) {
    const float* X0      = (const float*)d_in[0];
    const int*   edgesrc = (const int*)d_in[1];
    const int*   edgedst = (const int*)d_in[2];
    const float* bn0g = (const float*)d_in[3];
    const float* bn0b = (const float*)d_in[4];
    const float* W1   = (const float*)d_in[5];
    const float* bn1g = (const float*)d_in[7];
    const float* bn1b = (const float*)d_in[8];
    const float* W2   = (const float*)d_in[9];
    const float* bn2g = (const float*)d_in[11];
    const float* bn2b = (const float*)d_in[12];
    const float* Wf   = (const float*)d_in[13];
    const float* bfv  = (const float*)d_in[14];

    const int n = in_sizes[0] / 128;
    const int e = in_sizes[1];
    float* OUT = (float*)d_out;

    const int aggBlocks = (n + 3) / 4;               // one wave per node

    // workspace layout
    ushort* H    = (ushort*)d_ws;                     // n*128 bf16
    ushort* AGGb = H + (size_t)n * 128;               // n*128 bf16
    float*  dinv = (float*)(AGGb + (size_t)n * 128);  // n
    int2*   ep   = (int2*)(dinv + n);                 // e
    ushort* Wswz = (ushort*)(ep + e);                 // 2 * 16384 bf16
    int*    cnt  = (int*)(Wswz + 2 * 16384);          // n
    int*    rs   = cnt + n;                           // n+1
    int*    rank = rs + n + 1;                        // e
    int*    bsum = rank + e;                          // 64
    float*  part = (float*)(bsum + 64);               // aggBlocks*256 (12.8MB)
    float* part2 = part + (size_t)aggBlocks * 256;    // 64*256

    const float invn = 1.f / (float)n;
    const int nb = (n + 1023) / 1024;
    const int fillBlocks = (e + 255) / 256;
    const int scanBlocks = (n + 255) / 256;
    const int gemmBlocks = (n + 63) / 64;

    // 1. fused prologue: colstats(X0) + W swizzle + cnt zero
    k_prolog<<<CS_BLOCKS + 16 + 64, 256, 0, stream>>>(X0, n, part, W1, W2,
                                                      Wswz, cnt);
    // 2-4. CSR build (scanC carries layer-1 redA role)
    k_count<<<(e + 255) / 256, 256, 0, stream>>>(edgedst, e, cnt, rank);
    k_scanA<<<nb, 1024, 0, stream>>>(cnt, n, rs, bsum);
    k_scanC<<<scanBlocks + 64, 256, 0, stream>>>(rs, bsum, cnt, dinv, n, e,
                                                 part, part2, scanBlocks);
    // 5. layer-1 GEMM + CSR fill (independent roles)
    k_gemm_fill<<<gemmBlocks + fillBlocks, 256, 0, stream>>>(
        X0, Wswz, part2, bn0g, bn0b, invn, H, n, gemmBlocks,
        edgesrc, edgedst, e, rs, rank, dinv, ep);
    // 6. aggregate 1 (+ fused BN1 stats)
    k_aggregate<<<aggBlocks, 256, 0, stream>>>(H, rs, ep, dinv, AGGb, part, n);
    // 7-8. layer 2
    k_redA<<<64, 256, 0, stream>>>(part, part2, aggBlocks);
    k_gemm_mfma<<<gemmBlocks, 256, 0, stream>>>(AGGb, Wswz + 16384, part2,
                                                bn1g, bn1b, invn, 1, H, n);
    // 9. aggregate 2 (+ fused BN2 stats)
    k_aggregate<<<aggBlocks, 256, 0, stream>>>(H, rs, ep, dinv, AGGb, part, n);
    // 10-11. head
    k_redA<<<64, 256, 0, stream>>>(part, part2, aggBlocks);
    k_gemm_out<<<(n + 31) / 32, 256, 0, stream>>>(AGGb, Wf, bfv, part2, bn2g,
                                                  bn2b, invn, OUT, n);
}